// Round 1
// baseline (513.399 us; speedup 1.0000x reference)
//
#include <hip/hip_runtime.h>
#include <math.h>

#define FI4(p) (*(const float4*)(p))

__device__ __forceinline__ float gumbelf(float u) {
    return -__logf(-__logf(u + 1e-9f) + 1e-9f);
}

// ---------------------------------------------------------------------------
// eo = silu(emb) @ W^T + b   for the 4 AdaLN linears (l=0..2 branches, l=3 xf)
// one wave per output element; eo layout [l][b][1024]
// ---------------------------------------------------------------------------
__global__ __launch_bounds__(256) void eo_kernel(
    const float* __restrict__ emb,
    const float* __restrict__ adaln_w, const float* __restrict__ adaln_b,
    const float* __restrict__ xfn_w,  const float* __restrict__ xfn_b,
    float* __restrict__ eo)
{
    int wid  = blockIdx.x * 4 + (threadIdx.x >> 6);
    int lane = threadIdx.x & 63;
    int l = wid >> 12;
    int rem = wid & 4095;
    int b = rem >> 10;
    int o = rem & 1023;
    const float* wrow = (l < 3) ? (adaln_w + ((size_t)(l * 1024 + o)) * 512)
                                : (xfn_w + (size_t)o * 512);
    const float* erow = emb + b * 512;
    float acc = 0.f;
    for (int d = lane; d < 512; d += 64) {
        float e = erow[d];
        float se = e / (1.f + __expf(-e));   // silu
        acc = fmaf(se, wrow[d], acc);
    }
    #pragma unroll
    for (int off = 32; off; off >>= 1) acc += __shfl_xor(acc, off, 64);
    if (lane == 0) {
        float bias = (l < 3) ? adaln_b[l * 1024 + o] : xfn_b[o];
        eo[wid] = acc + bias;
    }
}

// ---------------------------------------------------------------------------
// LayerNorm (biased var) + modulation: rows 0..6143 -> xnq (x1|x2|x3),
// rows 6144..22527 -> xfn (xf).  One 256-thread block per 512-wide row.
// ---------------------------------------------------------------------------
__global__ __launch_bounds__(256) void ln_kernel(
    const float* __restrict__ x1, const float* __restrict__ x2,
    const float* __restrict__ x3, const float* __restrict__ xf,
    const float* __restrict__ eo,
    float* __restrict__ xnq, float* __restrict__ xfnb)
{
    int row = blockIdx.x;
    const float* src; const float* eorow; float* dst;
    if (row < 6144) {
        int l = row >> 11, idx = row & 2047, b = idx >> 9;
        const float* xp = (l == 0) ? x1 : (l == 1) ? x2 : x3;
        src = xp + (size_t)idx * 512;
        eorow = eo + (size_t)(l * 4 + b) * 1024;
        dst = xnq + (size_t)row * 512;
    } else {
        int rr = row - 6144; int b = rr >> 12;
        src = xf + (size_t)rr * 512;
        eorow = eo + (size_t)(12 + b) * 1024;
        dst = xfnb + (size_t)rr * 512;
    }
    int tid = threadIdx.x;
    float v0 = src[tid], v1 = src[tid + 256];
    float s = v0 + v1;
    float q = fmaf(v0, v0, v1 * v1);
    #pragma unroll
    for (int off = 32; off; off >>= 1) {
        s += __shfl_xor(s, off, 64);
        q += __shfl_xor(q, off, 64);
    }
    __shared__ float red[8];
    int wv = tid >> 6, lane = tid & 63;
    if (lane == 0) { red[wv] = s; red[4 + wv] = q; }
    __syncthreads();
    s = red[0] + red[1] + red[2] + red[3];
    q = red[4] + red[5] + red[6] + red[7];
    float mu  = s * (1.f / 512.f);
    float var = q * (1.f / 512.f) - mu * mu;
    float rs  = 1.f / sqrtf(var + 1e-6f);
    dst[tid]       = (v0 - mu) * rs * (1.f + eorow[tid])       + eorow[512 + tid];
    dst[tid + 256] = (v1 - mu) * rs * (1.f + eorow[tid + 256]) + eorow[768 + tid];
}

// ---------------------------------------------------------------------------
// Generic f32 GEMM  C = A(rows x Kdim) * W^T (+bias), tile 128x64, BK=32,
// micro 8x4 with split row-quads (conflict-free ds_read_b128).
// mode 0: Q proj   (A=xnq 6144x512,  W=q_w[l],        C=Qb  [bh][1536][36])
// mode 1: K/V proj (A=xfn 16384x512, W=k_w[h]/v_w[h], C=Kb/Vb [bh][512][36])
// mode 2: out proj (A=att 6144x288,  W=out_w[l],      C=d_out)
// ---------------------------------------------------------------------------
__global__ __launch_bounds__(256) void gemm_kernel(
    int mode,
    const float* __restrict__ A,
    const float* __restrict__ W0, const float* __restrict__ W1,
    const float* __restrict__ B0, const float* __restrict__ B1,
    float* __restrict__ C0, float* __restrict__ C1,
    int NB)
{
    __shared__ float A_s[32][132];
    __shared__ float W_s[32][68];

    const int tid = threadIdx.x;
    const int mb = blockIdx.x / NB, nb = blockIdx.x % NB;
    const int row0 = mb * 128, o0 = nb * 64;
    const int Kdim = (mode == 2) ? 288 : 512;
    const int OUTS = (mode == 0) ? 288 : (mode == 1) ? 72 : 512;

    int l = 0, h = 0;
    if (mode == 1) h = (row0 >> 9) & 7;
    else           l = row0 >> 11;

    // A-row base (mode 2 reads the [b][1536][288] attention buffer)
    size_t arow0;
    if (mode == 2) {
        int rb = row0 & 2047; int bb = rb >> 9; int tb = row0 & 511;
        arow0 = (size_t)bb * 1536 + (size_t)l * 512 + tb;
    } else {
        arow0 = (size_t)row0;
    }

    const int lk = tid & 31, lr = tid >> 5;
    float acc[8][4];
    #pragma unroll
    for (int i = 0; i < 8; ++i)
        #pragma unroll
        for (int j = 0; j < 4; ++j) acc[i][j] = 0.f;

    for (int kt = 0; kt < Kdim; kt += 32) {
        #pragma unroll
        for (int i = 0; i < 16; ++i) {
            int m = lr + 8 * i;
            A_s[lk][m] = A[(arow0 + m) * Kdim + kt + lk];
        }
        #pragma unroll
        for (int i = 0; i < 8; ++i) {
            int o = lr + 8 * i;
            int og = o0 + o;
            float val = 0.f;
            if (og < OUTS) {
                const float* wr;
                if (mode == 0)      wr = W0 + ((size_t)(l * 288 + og)) * 512;
                else if (mode == 1) wr = (og < 36) ? W0 + ((size_t)(h * 36 + og)) * 512
                                                   : W1 + ((size_t)(h * 36 + og - 36)) * 512;
                else                wr = W0 + ((size_t)(l * 512 + og)) * 288;
                val = wr[kt + lk];
            }
            W_s[lk][o] = val;
        }
        __syncthreads();
        #pragma unroll
        for (int kk = 0; kk < 32; ++kk) {
            float4 a0 = FI4(&A_s[kk][4 * (tid & 15)]);
            float4 a1 = FI4(&A_s[kk][64 + 4 * (tid & 15)]);
            float4 w  = FI4(&W_s[kk][4 * (tid >> 4)]);
            float av[8] = {a0.x, a0.y, a0.z, a0.w, a1.x, a1.y, a1.z, a1.w};
            float wvv[4] = {w.x, w.y, w.z, w.w};
            #pragma unroll
            for (int i = 0; i < 8; ++i)
                #pragma unroll
                for (int j = 0; j < 4; ++j)
                    acc[i][j] = fmaf(av[i], wvv[j], acc[i][j]);
        }
        __syncthreads();
    }

    const int tm = tid & 15, tn = tid >> 4;
    const int cb = o0 + 4 * tn;
    if (cb >= OUTS) return;

    #pragma unroll
    for (int half = 0; half < 2; ++half) {
        #pragma unroll
        for (int i = 0; i < 4; ++i) {
            int r = row0 + half * 64 + 4 * tm + i;
            float4 v;
            if (mode == 0) {
                int rb = r & 2047; int bb = rb >> 9; int t = rb & 511;
                int tgl = l * 512 + t;
                int hh = cb / 36; int hd = cb - hh * 36;
                v.x = acc[half * 4 + i][0] + B0[l * 288 + cb + 0];
                v.y = acc[half * 4 + i][1] + B0[l * 288 + cb + 1];
                v.z = acc[half * 4 + i][2] + B0[l * 288 + cb + 2];
                v.w = acc[half * 4 + i][3] + B0[l * 288 + cb + 3];
                *(float4*)&C0[(((size_t)bb * 8 + hh) * 1536 + tgl) * 36 + hd] = v;
            } else if (mode == 1) {
                int bb = r >> 12; int nn = r & 511;
                if (cb < 36) {
                    v.x = acc[half * 4 + i][0] + B0[h * 36 + cb + 0];
                    v.y = acc[half * 4 + i][1] + B0[h * 36 + cb + 1];
                    v.z = acc[half * 4 + i][2] + B0[h * 36 + cb + 2];
                    v.w = acc[half * 4 + i][3] + B0[h * 36 + cb + 3];
                    *(float4*)&C0[(((size_t)bb * 8 + h) * 512 + nn) * 36 + cb] = v;
                } else {
                    int c2 = cb - 36;
                    v.x = acc[half * 4 + i][0] + B1[h * 36 + c2 + 0];
                    v.y = acc[half * 4 + i][1] + B1[h * 36 + c2 + 1];
                    v.z = acc[half * 4 + i][2] + B1[h * 36 + c2 + 2];
                    v.w = acc[half * 4 + i][3] + B1[h * 36 + c2 + 3];
                    *(float4*)&C1[(((size_t)bb * 8 + h) * 512 + nn) * 36 + c2] = v;
                }
            } else {
                int rb = r & 2047; int bb = rb >> 9; int t = rb & 511;
                v.x = acc[half * 4 + i][0] + B0[l * 512 + cb + 0];
                v.y = acc[half * 4 + i][1] + B0[l * 512 + cb + 1];
                v.z = acc[half * 4 + i][2] + B0[l * 512 + cb + 2];
                v.w = acc[half * 4 + i][3] + B0[l * 512 + cb + 3];
                *(float4*)&C0[(size_t)l * 1048576 + ((size_t)bb * 512 + t) * 512 + cb] = v;
            }
        }
    }
}

// ---------------------------------------------------------------------------
// Attention: per (b,h) stage K (d-major, quad-XOR-swizzled) + V (n-major) in
// LDS; each block handles 192 t-rows (3 iters x 64). 512 threads: each 32-lane
// group owns 4 t-rows; QK^T in registers, gumbel, iterative top-16, hard
// softmax, 16-term sparse PV gather.
// ---------------------------------------------------------------------------
__global__ __launch_bounds__(512) void attn_kernel(
    const float* __restrict__ Qb, const float* __restrict__ Kb,
    const float* __restrict__ Vb, const float* __restrict__ un,
    float* __restrict__ att)
{
    __shared__ float K_s[36 * 512];
    __shared__ float V_s[512 * 36];
    __shared__ float Q_s[36 * 64];

    const int tid = threadIdx.x;
    const int bh = blockIdx.x >> 3;
    const int chunk = blockIdx.x & 7;
    const int b = bh >> 3, h = bh & 7;
    const int lane32 = tid & 31;
    const int tg = tid >> 5;

    const float* Ksrc = Kb + (size_t)bh * (512 * 36);
    for (int idx = tid; idx < 512 * 36; idx += 512) {
        int n = idx / 36;
        int d = idx - n * 36;
        K_s[d * 512 + (n ^ ((d & 7) << 2))] = Ksrc[idx];
    }
    const float* Vsrc = Vb + (size_t)bh * (512 * 36);
    for (int idx = tid; idx < 512 * 36; idx += 512) V_s[idx] = Vsrc[idx];

    for (int it = 0; it < 3; ++it) {
        const int t0 = chunk * 192 + it * 64;
        __syncthreads();
        for (int idx = tid; idx < 64 * 36; idx += 512) {
            int tt = idx / 36;
            int d = idx - tt * 36;
            Q_s[d * 64 + tt] = Qb[((size_t)bh * 1536 + t0 + tt) * 36 + d];
        }
        __syncthreads();

        float acc[4][16];
        #pragma unroll
        for (int i = 0; i < 4; ++i)
            #pragma unroll
            for (int j = 0; j < 16; ++j) acc[i][j] = 0.f;

        #pragma unroll 6
        for (int d = 0; d < 36; ++d) {
            float4 q4 = FI4(&Q_s[d * 64 + tg * 4]);
            int sw = (d & 7) << 2;
            int kb = d * 512;
            float4 k0 = FI4(&K_s[kb + ((lane32 * 4      ) ^ sw)]);
            float4 k1 = FI4(&K_s[kb + ((lane32 * 4 + 128) ^ sw)]);
            float4 k2 = FI4(&K_s[kb + ((lane32 * 4 + 256) ^ sw)]);
            float4 k3 = FI4(&K_s[kb + ((lane32 * 4 + 384) ^ sw)]);
            float qv[4] = {q4.x, q4.y, q4.z, q4.w};
            float kv[16] = {k0.x, k0.y, k0.z, k0.w, k1.x, k1.y, k1.z, k1.w,
                            k2.x, k2.y, k2.z, k2.w, k3.x, k3.y, k3.z, k3.w};
            #pragma unroll
            for (int i = 0; i < 4; ++i)
                #pragma unroll
                for (int j = 0; j < 16; ++j)
                    acc[i][j] = fmaf(qv[i], kv[j], acc[i][j]);
        }

        // logits = QK/6 + gumbel
        #pragma unroll
        for (int i = 0; i < 4; ++i) {
            const int t = t0 + tg * 4 + i;
            const float* urow = un + ((size_t)bh * 1536 + t) * 512;
            #pragma unroll
            for (int jj = 0; jj < 4; ++jj) {
                float4 u = FI4(&urow[lane32 * 4 + 128 * jj]);
                acc[i][jj * 4 + 0] = acc[i][jj * 4 + 0] / 6.0f + gumbelf(u.x);
                acc[i][jj * 4 + 1] = acc[i][jj * 4 + 1] / 6.0f + gumbelf(u.y);
                acc[i][jj * 4 + 2] = acc[i][jj * 4 + 2] / 6.0f + gumbelf(u.z);
                acc[i][jj * 4 + 3] = acc[i][jj * 4 + 3] / 6.0f + gumbelf(u.w);
            }
        }

        #pragma unroll
        for (int i = 0; i < 4; ++i) {
            unsigned alive = 0xFFFFu;
            float wv[16]; int wn[16];
            #pragma unroll
            for (int k = 0; k < 16; ++k) {
                float bv = -INFINITY; int bj = 0;
                #pragma unroll
                for (int j = 0; j < 16; ++j) {
                    float lv = (alive & (1u << j)) ? acc[i][j] : -INFINITY;
                    if (lv > bv) { bv = lv; bj = j; }   // first hit => smaller n on tie
                }
                int bn = lane32 * 4 + ((bj >> 2) << 7) + (bj & 3);
                #pragma unroll
                for (int off = 1; off < 32; off <<= 1) {
                    float ov = __shfl_xor(bv, off, 32);
                    int   on = __shfl_xor(bn, off, 32);
                    if (ov > bv || (ov == bv && on < bn)) { bv = ov; bn = on; }
                }
                wv[k] = bv; wn[k] = bn;
                if (((bn >> 2) & 31) == lane32)
                    alive &= ~(1u << (((bn >> 7) << 2) | (bn & 3)));
            }
            float m = wv[0];
            float e[16]; float ssum = 0.f;
            #pragma unroll
            for (int k = 0; k < 16; ++k) { e[k] = __expf(wv[k] - m); ssum += e[k]; }
            float inv = 1.0f / ssum;
            float o1 = 0.f, o2 = 0.f;
            #pragma unroll
            for (int k = 0; k < 16; ++k) {
                float w = e[k] * inv;
                const float* vr = &V_s[wn[k] * 36];
                float v2 = (lane32 < 4) ? vr[lane32 + 32] : 0.f;
                o1 = fmaf(w, vr[lane32], o1);
                o2 = fmaf(w, v2, o2);
            }
            const int t = t0 + tg * 4 + i;
            float* orow = att + ((size_t)b * 1536 + t) * 288 + h * 36;
            orow[lane32] = o1;
            if (lane32 < 4) orow[lane32 + 32] = o2;
        }
    }
}

// ---------------------------------------------------------------------------
extern "C" void kernel_launch(void* const* d_in, const int* in_sizes, int n_in,
                              void* d_out, int out_size, void* d_ws, size_t ws_size,
                              hipStream_t stream)
{
    (void)in_sizes; (void)n_in; (void)out_size; (void)ws_size;
    const float* x1      = (const float*)d_in[0];
    const float* x2      = (const float*)d_in[1];
    const float* x3      = (const float*)d_in[2];
    const float* xf      = (const float*)d_in[3];
    const float* emb     = (const float*)d_in[4];
    const float* un      = (const float*)d_in[5];
    const float* adaln_w = (const float*)d_in[6];
    const float* adaln_b = (const float*)d_in[7];
    const float* xfn_w   = (const float*)d_in[8];
    const float* xfn_b   = (const float*)d_in[9];
    const float* q_w     = (const float*)d_in[10];
    const float* q_b     = (const float*)d_in[11];
    const float* k_w     = (const float*)d_in[12];
    const float* k_b     = (const float*)d_in[13];
    const float* v_w     = (const float*)d_in[14];
    const float* v_b     = (const float*)d_in[15];
    const float* out_w   = (const float*)d_in[16];
    const float* out_b   = (const float*)d_in[17];
    float* out = (float*)d_out;

    float* ws   = (float*)d_ws;
    float* eo   = ws;                       // 16384
    float* xnq  = eo  + 16384;              // 6144*512
    float* xfn  = xnq + 6144 * 512;         // 16384*512
    float* Qb   = xfn + 16384 * 512;        // 32*1536*36
    float* Kb   = Qb  + 32 * 1536 * 36;     // 32*512*36
    float* Vb   = Kb  + 32 * 512 * 36;      // 32*512*36
    float* att  = Vb  + 32 * 512 * 36;      // 6144*288

    eo_kernel<<<4096, 256, 0, stream>>>(emb, adaln_w, adaln_b, xfn_w, xfn_b, eo);
    ln_kernel<<<22528, 256, 0, stream>>>(x1, x2, x3, xf, eo, xnq, xfn);
    gemm_kernel<<<48 * 5, 256, 0, stream>>>(0, xnq, q_w, nullptr, q_b, nullptr, Qb, nullptr, 5);
    gemm_kernel<<<128 * 2, 256, 0, stream>>>(1, xfn, k_w, v_w, k_b, v_b, Kb, Vb, 2);
    attn_kernel<<<256, 512, 0, stream>>>(Qb, Kb, Vb, un, att);
    gemm_kernel<<<48 * 8, 256, 0, stream>>>(2, att, out_w, nullptr, out_b, nullptr, out, nullptr, 8);
}

// Round 2
// 501.259 us; speedup vs baseline: 1.0242x; 1.0242x over previous
//
#include <hip/hip_runtime.h>
#include <math.h>

#define FI4(p) (*(const float4*)(p))

__device__ __forceinline__ float gumbelf(float u) {
    return -__logf(-__logf(u + 1e-9f) + 1e-9f);
}

// ---------------------------------------------------------------------------
// eo = silu(emb) @ W^T + b   for the 4 AdaLN linears (l=0..2 branches, l=3 xf)
// one wave per output element; eo layout [l][b][1024]
// ---------------------------------------------------------------------------
__global__ __launch_bounds__(256) void eo_kernel(
    const float* __restrict__ emb,
    const float* __restrict__ adaln_w, const float* __restrict__ adaln_b,
    const float* __restrict__ xfn_w,  const float* __restrict__ xfn_b,
    float* __restrict__ eo)
{
    int wid  = blockIdx.x * 4 + (threadIdx.x >> 6);
    int lane = threadIdx.x & 63;
    int l = wid >> 12;
    int rem = wid & 4095;
    int b = rem >> 10;
    int o = rem & 1023;
    const float* wrow = (l < 3) ? (adaln_w + ((size_t)(l * 1024 + o)) * 512)
                                : (xfn_w + (size_t)o * 512);
    const float* erow = emb + b * 512;
    float acc = 0.f;
    for (int d = lane; d < 512; d += 64) {
        float e = erow[d];
        float se = e / (1.f + __expf(-e));   // silu
        acc = fmaf(se, wrow[d], acc);
    }
    #pragma unroll
    for (int off = 32; off; off >>= 1) acc += __shfl_xor(acc, off, 64);
    if (lane == 0) {
        float bias = (l < 3) ? adaln_b[l * 1024 + o] : xfn_b[o];
        eo[wid] = acc + bias;
    }
}

// ---------------------------------------------------------------------------
// LayerNorm (biased var) + modulation: rows 0..6143 -> xnq (x1|x2|x3),
// rows 6144..22527 -> xfn (xf).  One 256-thread block per 512-wide row.
// ---------------------------------------------------------------------------
__global__ __launch_bounds__(256) void ln_kernel(
    const float* __restrict__ x1, const float* __restrict__ x2,
    const float* __restrict__ x3, const float* __restrict__ xf,
    const float* __restrict__ eo,
    float* __restrict__ xnq, float* __restrict__ xfnb)
{
    int row = blockIdx.x;
    const float* src; const float* eorow; float* dst;
    if (row < 6144) {
        int l = row >> 11, idx = row & 2047, b = idx >> 9;
        const float* xp = (l == 0) ? x1 : (l == 1) ? x2 : x3;
        src = xp + (size_t)idx * 512;
        eorow = eo + (size_t)(l * 4 + b) * 1024;
        dst = xnq + (size_t)row * 512;
    } else {
        int rr = row - 6144; int b = rr >> 12;
        src = xf + (size_t)rr * 512;
        eorow = eo + (size_t)(12 + b) * 1024;
        dst = xfnb + (size_t)rr * 512;
    }
    int tid = threadIdx.x;
    float v0 = src[tid], v1 = src[tid + 256];
    float s = v0 + v1;
    float q = fmaf(v0, v0, v1 * v1);
    #pragma unroll
    for (int off = 32; off; off >>= 1) {
        s += __shfl_xor(s, off, 64);
        q += __shfl_xor(q, off, 64);
    }
    __shared__ float red[8];
    int wv = tid >> 6, lane = tid & 63;
    if (lane == 0) { red[wv] = s; red[4 + wv] = q; }
    __syncthreads();
    s = red[0] + red[1] + red[2] + red[3];
    q = red[4] + red[5] + red[6] + red[7];
    float mu  = s * (1.f / 512.f);
    float var = q * (1.f / 512.f) - mu * mu;
    float rs  = 1.f / sqrtf(var + 1e-6f);
    dst[tid]       = (v0 - mu) * rs * (1.f + eorow[tid])       + eorow[512 + tid];
    dst[tid + 256] = (v1 - mu) * rs * (1.f + eorow[tid + 256]) + eorow[768 + tid];
}

// ---------------------------------------------------------------------------
// Generic f32 GEMM  C = A(rows x Kdim) * W^T (+bias), tile 128x64, BK=32,
// micro 8x4 with split row-quads (conflict-free ds_read_b128).
// mode 0: Q proj   (A=xnq 6144x512,  W=q_w[l],        C=Qb  [bh][1536][36])
// mode 1: K/V proj (A=xfn 16384x512, W=k_w[h]/v_w[h], C=Kb/Vb [bh][512][36])
// mode 2: out proj (A=att 6144x288,  W=out_w[l],      C=d_out)
// ---------------------------------------------------------------------------
__global__ __launch_bounds__(256) void gemm_kernel(
    int mode,
    const float* __restrict__ A,
    const float* __restrict__ W0, const float* __restrict__ W1,
    const float* __restrict__ B0, const float* __restrict__ B1,
    float* __restrict__ C0, float* __restrict__ C1,
    int NB)
{
    __shared__ float A_s[32][132];
    __shared__ float W_s[32][68];

    const int tid = threadIdx.x;
    const int mb = blockIdx.x / NB, nb = blockIdx.x % NB;
    const int row0 = mb * 128, o0 = nb * 64;
    const int Kdim = (mode == 2) ? 288 : 512;
    const int OUTS = (mode == 0) ? 288 : (mode == 1) ? 72 : 512;

    int l = 0, h = 0;
    if (mode == 1) h = (row0 >> 9) & 7;
    else           l = row0 >> 11;

    // A-row base (mode 2 reads the [b][1536][288] attention buffer)
    size_t arow0;
    if (mode == 2) {
        int rb = row0 & 2047; int bb = rb >> 9; int tb = row0 & 511;
        arow0 = (size_t)bb * 1536 + (size_t)l * 512 + tb;
    } else {
        arow0 = (size_t)row0;
    }

    const int lk = tid & 31, lr = tid >> 5;
    float acc[8][4];
    #pragma unroll
    for (int i = 0; i < 8; ++i)
        #pragma unroll
        for (int j = 0; j < 4; ++j) acc[i][j] = 0.f;

    for (int kt = 0; kt < Kdim; kt += 32) {
        #pragma unroll
        for (int i = 0; i < 16; ++i) {
            int m = lr + 8 * i;
            A_s[lk][m] = A[(arow0 + m) * Kdim + kt + lk];
        }
        #pragma unroll
        for (int i = 0; i < 8; ++i) {
            int o = lr + 8 * i;
            int og = o0 + o;
            float val = 0.f;
            if (og < OUTS) {
                const float* wr;
                if (mode == 0)      wr = W0 + ((size_t)(l * 288 + og)) * 512;
                else if (mode == 1) wr = (og < 36) ? W0 + ((size_t)(h * 36 + og)) * 512
                                                   : W1 + ((size_t)(h * 36 + og - 36)) * 512;
                else                wr = W0 + ((size_t)(l * 512 + og)) * 288;
                val = wr[kt + lk];
            }
            W_s[lk][o] = val;
        }
        __syncthreads();
        #pragma unroll
        for (int kk = 0; kk < 32; ++kk) {
            float4 a0 = FI4(&A_s[kk][4 * (tid & 15)]);
            float4 a1 = FI4(&A_s[kk][64 + 4 * (tid & 15)]);
            float4 w  = FI4(&W_s[kk][4 * (tid >> 4)]);
            float av[8] = {a0.x, a0.y, a0.z, a0.w, a1.x, a1.y, a1.z, a1.w};
            float wvv[4] = {w.x, w.y, w.z, w.w};
            #pragma unroll
            for (int i = 0; i < 8; ++i)
                #pragma unroll
                for (int j = 0; j < 4; ++j)
                    acc[i][j] = fmaf(av[i], wvv[j], acc[i][j]);
        }
        __syncthreads();
    }

    const int tm = tid & 15, tn = tid >> 4;
    const int cb = o0 + 4 * tn;
    if (cb >= OUTS) return;

    #pragma unroll
    for (int half = 0; half < 2; ++half) {
        #pragma unroll
        for (int i = 0; i < 4; ++i) {
            int r = row0 + half * 64 + 4 * tm + i;
            float4 v;
            if (mode == 0) {
                int rb = r & 2047; int bb = rb >> 9; int t = rb & 511;
                int tgl = l * 512 + t;
                int hh = cb / 36; int hd = cb - hh * 36;
                v.x = acc[half * 4 + i][0] + B0[l * 288 + cb + 0];
                v.y = acc[half * 4 + i][1] + B0[l * 288 + cb + 1];
                v.z = acc[half * 4 + i][2] + B0[l * 288 + cb + 2];
                v.w = acc[half * 4 + i][3] + B0[l * 288 + cb + 3];
                *(float4*)&C0[(((size_t)bb * 8 + hh) * 1536 + tgl) * 36 + hd] = v;
            } else if (mode == 1) {
                int bb = r >> 12; int nn = r & 511;
                if (cb < 36) {
                    v.x = acc[half * 4 + i][0] + B0[h * 36 + cb + 0];
                    v.y = acc[half * 4 + i][1] + B0[h * 36 + cb + 1];
                    v.z = acc[half * 4 + i][2] + B0[h * 36 + cb + 2];
                    v.w = acc[half * 4 + i][3] + B0[h * 36 + cb + 3];
                    *(float4*)&C0[(((size_t)bb * 8 + h) * 512 + nn) * 36 + cb] = v;
                } else {
                    int c2 = cb - 36;
                    v.x = acc[half * 4 + i][0] + B1[h * 36 + c2 + 0];
                    v.y = acc[half * 4 + i][1] + B1[h * 36 + c2 + 1];
                    v.z = acc[half * 4 + i][2] + B1[h * 36 + c2 + 2];
                    v.w = acc[half * 4 + i][3] + B1[h * 36 + c2 + 3];
                    *(float4*)&C1[(((size_t)bb * 8 + h) * 512 + nn) * 36 + c2] = v;
                }
            } else {
                int rb = r & 2047; int bb = rb >> 9; int t = rb & 511;
                v.x = acc[half * 4 + i][0] + B0[l * 512 + cb + 0];
                v.y = acc[half * 4 + i][1] + B0[l * 512 + cb + 1];
                v.z = acc[half * 4 + i][2] + B0[l * 512 + cb + 2];
                v.w = acc[half * 4 + i][3] + B0[l * 512 + cb + 3];
                *(float4*)&C0[(size_t)l * 1048576 + ((size_t)bb * 512 + t) * 512 + cb] = v;
            }
        }
    }
}

// ---------------------------------------------------------------------------
// Attention: per (b,h) stage K (d-major, quad-XOR-swizzled) + V (n-major) in
// LDS; each block handles 192 t-rows (3 iters x 64). 512 threads: each 32-lane
// group owns 4 t-rows; QK^T in registers, gumbel, iterative top-16, hard
// softmax, 16-term sparse PV gather.
// ---------------------------------------------------------------------------
__global__ __launch_bounds__(512) void attn_kernel(
    const float* __restrict__ Qb, const float* __restrict__ Kb,
    const float* __restrict__ Vb, const float* __restrict__ un,
    float* __restrict__ att)
{
    __shared__ float K_s[36 * 512];
    __shared__ float V_s[512 * 36];
    __shared__ float Q_s[36 * 64];

    const int tid = threadIdx.x;
    const int bh = blockIdx.x >> 3;
    const int chunk = blockIdx.x & 7;
    const int b = bh >> 3, h = bh & 7;
    const int lane32 = tid & 31;
    const int tg = tid >> 5;

    const float* Ksrc = Kb + (size_t)bh * (512 * 36);
    for (int idx = tid; idx < 512 * 36; idx += 512) {
        int n = idx / 36;
        int d = idx - n * 36;
        K_s[d * 512 + (n ^ ((d & 7) << 2))] = Ksrc[idx];
    }
    const float* Vsrc = Vb + (size_t)bh * (512 * 36);
    for (int idx = tid; idx < 512 * 36; idx += 512) V_s[idx] = Vsrc[idx];

    for (int it = 0; it < 3; ++it) {
        const int t0 = chunk * 192 + it * 64;
        __syncthreads();
        for (int idx = tid; idx < 64 * 36; idx += 512) {
            int tt = idx / 36;
            int d = idx - tt * 36;
            Q_s[d * 64 + tt] = Qb[((size_t)bh * 1536 + t0 + tt) * 36 + d];
        }
        __syncthreads();

        float acc[4][16];
        #pragma unroll
        for (int i = 0; i < 4; ++i)
            #pragma unroll
            for (int j = 0; j < 16; ++j) acc[i][j] = 0.f;

        #pragma unroll 6
        for (int d = 0; d < 36; ++d) {
            float4 q4 = FI4(&Q_s[d * 64 + tg * 4]);
            int sw = (d & 7) << 2;
            int kb = d * 512;
            float4 k0 = FI4(&K_s[kb + ((lane32 * 4      ) ^ sw)]);
            float4 k1 = FI4(&K_s[kb + ((lane32 * 4 + 128) ^ sw)]);
            float4 k2 = FI4(&K_s[kb + ((lane32 * 4 + 256) ^ sw)]);
            float4 k3 = FI4(&K_s[kb + ((lane32 * 4 + 384) ^ sw)]);
            float qv[4] = {q4.x, q4.y, q4.z, q4.w};
            float kv[16] = {k0.x, k0.y, k0.z, k0.w, k1.x, k1.y, k1.z, k1.w,
                            k2.x, k2.y, k2.z, k2.w, k3.x, k3.y, k3.z, k3.w};
            #pragma unroll
            for (int i = 0; i < 4; ++i)
                #pragma unroll
                for (int j = 0; j < 16; ++j)
                    acc[i][j] = fmaf(qv[i], kv[j], acc[i][j]);
        }

        // logits = QK/6 + gumbel
        #pragma unroll
        for (int i = 0; i < 4; ++i) {
            const int t = t0 + tg * 4 + i;
            const float* urow = un + ((size_t)bh * 1536 + t) * 512;
            #pragma unroll
            for (int jj = 0; jj < 4; ++jj) {
                float4 u = FI4(&urow[lane32 * 4 + 128 * jj]);
                acc[i][jj * 4 + 0] = acc[i][jj * 4 + 0] / 6.0f + gumbelf(u.x);
                acc[i][jj * 4 + 1] = acc[i][jj * 4 + 1] / 6.0f + gumbelf(u.y);
                acc[i][jj * 4 + 2] = acc[i][jj * 4 + 2] / 6.0f + gumbelf(u.z);
                acc[i][jj * 4 + 3] = acc[i][jj * 4 + 3] / 6.0f + gumbelf(u.w);
            }
        }

        #pragma unroll
        for (int i = 0; i < 4; ++i) {
            unsigned alive = 0xFFFFu;
            float wv[16]; int wn[16];
            #pragma unroll
            for (int k = 0; k < 16; ++k) {
                float bv = -INFINITY; int bj = 0;
                #pragma unroll
                for (int j = 0; j < 16; ++j) {
                    float lv = (alive & (1u << j)) ? acc[i][j] : -INFINITY;
                    if (lv > bv) { bv = lv; bj = j; }   // first hit => smaller n on tie
                }
                int bn = lane32 * 4 + ((bj >> 2) << 7) + (bj & 3);
                #pragma unroll
                for (int off = 1; off < 32; off <<= 1) {
                    float ov = __shfl_xor(bv, off, 32);
                    int   on = __shfl_xor(bn, off, 32);
                    if (ov > bv || (ov == bv && on < bn)) { bv = ov; bn = on; }
                }
                wv[k] = bv; wn[k] = bn;
                if (((bn >> 2) & 31) == lane32)
                    alive &= ~(1u << (((bn >> 7) << 2) | (bn & 3)));
            }
            float m = wv[0];
            float e[16]; float ssum = 0.f;
            #pragma unroll
            for (int k = 0; k < 16; ++k) { e[k] = __expf(wv[k] - m); ssum += e[k]; }
            float inv = 1.0f / ssum;
            float o1 = 0.f, o2 = 0.f;
            #pragma unroll
            for (int k = 0; k < 16; ++k) {
                float w = e[k] * inv;
                const float* vr = &V_s[wn[k] * 36];
                float v2 = (lane32 < 4) ? vr[lane32 + 32] : 0.f;
                o1 = fmaf(w, vr[lane32], o1);
                o2 = fmaf(w, v2, o2);
            }
            const int t = t0 + tg * 4 + i;
            float* orow = att + ((size_t)b * 1536 + t) * 288 + h * 36;
            orow[lane32] = o1;
            if (lane32 < 4) orow[lane32 + 32] = o2;
        }
    }
}

// ---------------------------------------------------------------------------
extern "C" void kernel_launch(void* const* d_in, const int* in_sizes, int n_in,
                              void* d_out, int out_size, void* d_ws, size_t ws_size,
                              hipStream_t stream)
{
    (void)in_sizes; (void)n_in; (void)out_size; (void)ws_size;
    const float* x1      = (const float*)d_in[0];
    const float* x2      = (const float*)d_in[1];
    const float* x3      = (const float*)d_in[2];
    const float* xf      = (const float*)d_in[3];
    const float* emb     = (const float*)d_in[4];
    const float* un      = (const float*)d_in[5];
    const float* adaln_w = (const float*)d_in[6];
    const float* adaln_b = (const float*)d_in[7];
    const float* xfn_w   = (const float*)d_in[8];
    const float* xfn_b   = (const float*)d_in[9];
    const float* q_w     = (const float*)d_in[10];
    const float* q_b     = (const float*)d_in[11];
    const float* k_w     = (const float*)d_in[12];
    const float* k_b     = (const float*)d_in[13];
    const float* v_w     = (const float*)d_in[14];
    const float* v_b     = (const float*)d_in[15];
    const float* out_w   = (const float*)d_in[16];
    const float* out_b   = (const float*)d_in[17];
    float* out = (float*)d_out;

    float* ws   = (float*)d_ws;
    float* eo   = ws;                       // 16384
    float* xnq  = eo  + 16384;              // 6144*512
    float* xfn  = xnq + 6144 * 512;         // 16384*512
    float* Qb   = xfn + 16384 * 512;        // 32*1536*36
    float* Kb   = Qb  + 32 * 1536 * 36;     // 32*512*36
    float* Vb   = Kb  + 32 * 512 * 36;      // 32*512*36
    float* att  = Vb  + 32 * 512 * 36;      // 6144*288

    eo_kernel<<<4096, 256, 0, stream>>>(emb, adaln_w, adaln_b, xfn_w, xfn_b, eo);
    ln_kernel<<<22528, 256, 0, stream>>>(x1, x2, x3, xf, eo, xnq, xfn);
    gemm_kernel<<<48 * 5, 256, 0, stream>>>(0, xnq, q_w, nullptr, q_b, nullptr, Qb, nullptr, 5);
    gemm_kernel<<<128 * 2, 256, 0, stream>>>(1, xfn, k_w, v_w, k_b, v_b, Kb, Vb, 2);
    attn_kernel<<<256, 512, 0, stream>>>(Qb, Kb, Vb, un, att);
    gemm_kernel<<<48 * 8, 256, 0, stream>>>(2, att, out_w, nullptr, out_b, nullptr, out, nullptr, 8);
}

// Round 4
// 399.019 us; speedup vs baseline: 1.2867x; 1.2562x over previous
//
#include <hip/hip_runtime.h>
#include <math.h>

#define FI4(p) (*(const float4*)(p))

__device__ __forceinline__ float gumbelf(float u) {
    return -__logf(-__logf(u + 1e-9f) + 1e-9f);
}

template<int CTRL>
__device__ __forceinline__ int dppmov(int v) {
    return __builtin_amdgcn_update_dpp(v, v, CTRL, 0xF, 0xF, false);
}
// 64-lane max, result broadcast (uniform) via readlane 63
__device__ __forceinline__ float wave_max_bcast(float v) {
    v = fmaxf(v, __int_as_float(dppmov<0xB1>(__float_as_int(v))));  // quad_perm xor1
    v = fmaxf(v, __int_as_float(dppmov<0x4E>(__float_as_int(v))));  // quad_perm xor2
    v = fmaxf(v, __int_as_float(dppmov<0x141>(__float_as_int(v)))); // row_half_mirror (xor4)
    v = fmaxf(v, __int_as_float(dppmov<0x140>(__float_as_int(v)))); // row_mirror (xor8)
    v = fmaxf(v, __int_as_float(dppmov<0x142>(__float_as_int(v)))); // row_bcast15
    v = fmaxf(v, __int_as_float(dppmov<0x143>(__float_as_int(v)))); // row_bcast31
    return __int_as_float(__builtin_amdgcn_readlane(__float_as_int(v), 63));
}
__device__ __forceinline__ unsigned wave_min_bcast_u32(unsigned v) {
    unsigned t;
    t = (unsigned)dppmov<0xB1>((int)v);  v = v < t ? v : t;
    t = (unsigned)dppmov<0x4E>((int)v);  v = v < t ? v : t;
    t = (unsigned)dppmov<0x141>((int)v); v = v < t ? v : t;
    t = (unsigned)dppmov<0x140>((int)v); v = v < t ? v : t;
    t = (unsigned)dppmov<0x142>((int)v); v = v < t ? v : t;
    t = (unsigned)dppmov<0x143>((int)v); v = v < t ? v : t;
    return (unsigned)__builtin_amdgcn_readlane((int)v, 63);
}

// compare-exchange keeping (larger val, then smaller n) at position i
__device__ __forceinline__ void ce(float& si, float& sj, int& ni, int& nj) {
    bool sw = (sj > si) || ((sj == si) && (nj < ni));
    float tv = sw ? sj : si; sj = sw ? si : sj; si = tv;
    int   tn = sw ? nj : ni; nj = sw ? ni : nj; ni = tn;
}
// Batcher odd-even merge sort, 8 elements, 19 CEs, descending
__device__ __forceinline__ void sort8(float* s, int* n) {
    ce(s[0],s[1],n[0],n[1]); ce(s[2],s[3],n[2],n[3]); ce(s[4],s[5],n[4],n[5]); ce(s[6],s[7],n[6],n[7]);
    ce(s[0],s[2],n[0],n[2]); ce(s[1],s[3],n[1],n[3]); ce(s[4],s[6],n[4],n[6]); ce(s[5],s[7],n[5],n[7]);
    ce(s[1],s[2],n[1],n[2]); ce(s[5],s[6],n[5],n[6]);
    ce(s[0],s[4],n[0],n[4]); ce(s[1],s[5],n[1],n[5]); ce(s[2],s[6],n[2],n[6]); ce(s[3],s[7],n[3],n[7]);
    ce(s[2],s[4],n[2],n[4]); ce(s[3],s[5],n[3],n[5]);
    ce(s[1],s[2],n[1],n[2]); ce(s[3],s[4],n[3],n[4]); ce(s[5],s[6],n[5],n[6]);
}

// ---------------------------------------------------------------------------
// eo = silu(emb) @ W^T + b   for the 4 AdaLN linears (l=0..2 branches, l=3 xf)
// ---------------------------------------------------------------------------
__global__ __launch_bounds__(256) void eo_kernel(
    const float* __restrict__ emb,
    const float* __restrict__ adaln_w, const float* __restrict__ adaln_b,
    const float* __restrict__ xfn_w,  const float* __restrict__ xfn_b,
    float* __restrict__ eo)
{
    int wid  = blockIdx.x * 4 + (threadIdx.x >> 6);
    int lane = threadIdx.x & 63;
    int l = wid >> 12;
    int rem = wid & 4095;
    int b = rem >> 10;
    int o = rem & 1023;
    const float* wrow = (l < 3) ? (adaln_w + ((size_t)(l * 1024 + o)) * 512)
                                : (xfn_w + (size_t)o * 512);
    const float* erow = emb + b * 512;
    float acc = 0.f;
    for (int d = lane; d < 512; d += 64) {
        float e = erow[d];
        float se = e / (1.f + __expf(-e));   // silu
        acc = fmaf(se, wrow[d], acc);
    }
    #pragma unroll
    for (int off = 32; off; off >>= 1) acc += __shfl_xor(acc, off, 64);
    if (lane == 0) {
        float bias = (l < 3) ? adaln_b[l * 1024 + o] : xfn_b[o];
        eo[wid] = acc + bias;
    }
}

// ---------------------------------------------------------------------------
// LayerNorm (biased var) + modulation
// ---------------------------------------------------------------------------
__global__ __launch_bounds__(256) void ln_kernel(
    const float* __restrict__ x1, const float* __restrict__ x2,
    const float* __restrict__ x3, const float* __restrict__ xf,
    const float* __restrict__ eo,
    float* __restrict__ xnq, float* __restrict__ xfnb)
{
    int row = blockIdx.x;
    const float* src; const float* eorow; float* dst;
    if (row < 6144) {
        int l = row >> 11, idx = row & 2047, b = idx >> 9;
        const float* xp = (l == 0) ? x1 : (l == 1) ? x2 : x3;
        src = xp + (size_t)idx * 512;
        eorow = eo + (size_t)(l * 4 + b) * 1024;
        dst = xnq + (size_t)row * 512;
    } else {
        int rr = row - 6144; int b = rr >> 12;
        src = xf + (size_t)rr * 512;
        eorow = eo + (size_t)(12 + b) * 1024;
        dst = xfnb + (size_t)rr * 512;
    }
    int tid = threadIdx.x;
    float v0 = src[tid], v1 = src[tid + 256];
    float s = v0 + v1;
    float q = fmaf(v0, v0, v1 * v1);
    #pragma unroll
    for (int off = 32; off; off >>= 1) {
        s += __shfl_xor(s, off, 64);
        q += __shfl_xor(q, off, 64);
    }
    __shared__ float red[8];
    int wv = tid >> 6, lane = tid & 63;
    if (lane == 0) { red[wv] = s; red[4 + wv] = q; }
    __syncthreads();
    s = red[0] + red[1] + red[2] + red[3];
    q = red[4] + red[5] + red[6] + red[7];
    float mu  = s * (1.f / 512.f);
    float var = q * (1.f / 512.f) - mu * mu;
    float rs  = 1.f / sqrtf(var + 1e-6f);
    dst[tid]       = (v0 - mu) * rs * (1.f + eorow[tid])       + eorow[512 + tid];
    dst[tid + 256] = (v1 - mu) * rs * (1.f + eorow[tid + 256]) + eorow[768 + tid];
}

// ---------------------------------------------------------------------------
// Generic f32 GEMM  C = A * W^T (+bias), tile 128x64, BK=32
// ---------------------------------------------------------------------------
__global__ __launch_bounds__(256) void gemm_kernel(
    int mode,
    const float* __restrict__ A,
    const float* __restrict__ W0, const float* __restrict__ W1,
    const float* __restrict__ B0, const float* __restrict__ B1,
    float* __restrict__ C0, float* __restrict__ C1,
    int NB)
{
    __shared__ float A_s[32][132];
    __shared__ float W_s[32][68];

    const int tid = threadIdx.x;
    const int mb = blockIdx.x / NB, nb = blockIdx.x % NB;
    const int row0 = mb * 128, o0 = nb * 64;
    const int Kdim = (mode == 2) ? 288 : 512;
    const int OUTS = (mode == 0) ? 288 : (mode == 1) ? 72 : 512;

    int l = 0, h = 0;
    if (mode == 1) h = (row0 >> 9) & 7;
    else           l = row0 >> 11;

    size_t arow0;
    if (mode == 2) {
        int rb = row0 & 2047; int bb = rb >> 9; int tb = row0 & 511;
        arow0 = (size_t)bb * 1536 + (size_t)l * 512 + tb;
    } else {
        arow0 = (size_t)row0;
    }

    const int lk = tid & 31, lr = tid >> 5;
    float acc[8][4];
    #pragma unroll
    for (int i = 0; i < 8; ++i)
        #pragma unroll
        for (int j = 0; j < 4; ++j) acc[i][j] = 0.f;

    for (int kt = 0; kt < Kdim; kt += 32) {
        #pragma unroll
        for (int i = 0; i < 16; ++i) {
            int m = lr + 8 * i;
            A_s[lk][m] = A[(arow0 + m) * Kdim + kt + lk];
        }
        #pragma unroll
        for (int i = 0; i < 8; ++i) {
            int o = lr + 8 * i;
            int og = o0 + o;
            float val = 0.f;
            if (og < OUTS) {
                const float* wr;
                if (mode == 0)      wr = W0 + ((size_t)(l * 288 + og)) * 512;
                else if (mode == 1) wr = (og < 36) ? W0 + ((size_t)(h * 36 + og)) * 512
                                                   : W1 + ((size_t)(h * 36 + og - 36)) * 512;
                else                wr = W0 + ((size_t)(l * 512 + og)) * 288;
                val = wr[kt + lk];
            }
            W_s[lk][o] = val;
        }
        __syncthreads();
        #pragma unroll
        for (int kk = 0; kk < 32; ++kk) {
            float4 a0 = FI4(&A_s[kk][4 * (tid & 15)]);
            float4 a1 = FI4(&A_s[kk][64 + 4 * (tid & 15)]);
            float4 w  = FI4(&W_s[kk][4 * (tid >> 4)]);
            float av[8] = {a0.x, a0.y, a0.z, a0.w, a1.x, a1.y, a1.z, a1.w};
            float wvv[4] = {w.x, w.y, w.z, w.w};
            #pragma unroll
            for (int i = 0; i < 8; ++i)
                #pragma unroll
                for (int j = 0; j < 4; ++j)
                    acc[i][j] = fmaf(av[i], wvv[j], acc[i][j]);
        }
        __syncthreads();
    }

    const int tm = tid & 15, tn = tid >> 4;
    const int cb = o0 + 4 * tn;
    if (cb >= OUTS) return;

    #pragma unroll
    for (int half = 0; half < 2; ++half) {
        #pragma unroll
        for (int i = 0; i < 4; ++i) {
            int r = row0 + half * 64 + 4 * tm + i;
            float4 v;
            if (mode == 0) {
                int rb = r & 2047; int bb = rb >> 9; int t = rb & 511;
                int tgl = l * 512 + t;
                int hh = cb / 36; int hd = cb - hh * 36;
                v.x = acc[half * 4 + i][0] + B0[l * 288 + cb + 0];
                v.y = acc[half * 4 + i][1] + B0[l * 288 + cb + 1];
                v.z = acc[half * 4 + i][2] + B0[l * 288 + cb + 2];
                v.w = acc[half * 4 + i][3] + B0[l * 288 + cb + 3];
                *(float4*)&C0[(((size_t)bb * 8 + hh) * 1536 + tgl) * 36 + hd] = v;
            } else if (mode == 1) {
                int bb = r >> 12; int nn = r & 511;
                if (cb < 36) {
                    v.x = acc[half * 4 + i][0] + B0[h * 36 + cb + 0];
                    v.y = acc[half * 4 + i][1] + B0[h * 36 + cb + 1];
                    v.z = acc[half * 4 + i][2] + B0[h * 36 + cb + 2];
                    v.w = acc[half * 4 + i][3] + B0[h * 36 + cb + 3];
                    *(float4*)&C0[(((size_t)bb * 8 + h) * 512 + nn) * 36 + cb] = v;
                } else {
                    int c2 = cb - 36;
                    v.x = acc[half * 4 + i][0] + B1[h * 36 + c2 + 0];
                    v.y = acc[half * 4 + i][1] + B1[h * 36 + c2 + 1];
                    v.z = acc[half * 4 + i][2] + B1[h * 36 + c2 + 2];
                    v.w = acc[half * 4 + i][3] + B1[h * 36 + c2 + 3];
                    *(float4*)&C1[(((size_t)bb * 8 + h) * 512 + nn) * 36 + c2] = v;
                }
            } else {
                int rb = r & 2047; int bb = rb >> 9; int t = rb & 511;
                v.x = acc[half * 4 + i][0] + B0[l * 512 + cb + 0];
                v.y = acc[half * 4 + i][1] + B0[l * 512 + cb + 1];
                v.z = acc[half * 4 + i][2] + B0[l * 512 + cb + 2];
                v.w = acc[half * 4 + i][3] + B0[l * 512 + cb + 3];
                *(float4*)&C0[(size_t)l * 1048576 + ((size_t)bb * 512 + t) * 512 + cb] = v;
            }
        }
    }
}

// ---------------------------------------------------------------------------
// Attention v2: 512 blocks (2/CU), 512 thr. K in LDS [36][512]; Q staged
// 32 rows/pass; wave = selection domain (8 slots/lane). Per-lane sorted-8
// list + DPP max/min reduces (VALU pipe). V gathered from global (L2).
// ---------------------------------------------------------------------------
__global__ __launch_bounds__(512, 4) void attn_kernel(
    const float* __restrict__ Qb, const float* __restrict__ Kb,
    const float* __restrict__ Vb, const float* __restrict__ un,
    float* __restrict__ att)
{
    __shared__ float K_s[36 * 512];
    __shared__ float Q_s[36 * 32];

    const int tid = threadIdx.x;
    const int bh = blockIdx.x >> 4;
    const int chunk = blockIdx.x & 15;
    const int b = bh >> 3, h = bh & 7;
    const int l = tid & 63;
    const int w4 = (tid >> 6) * 4;          // wave's 4-row base within the 32-row pass
    const float S6 = 1.0f / 6.0f;

    // ---- stage K: thread t handles K row t -> K_s[d][t] (conflict-free writes)
    {
        const float4* kr = (const float4*)(Kb + ((size_t)bh * 512 + tid) * 36);
        float kv[36];
        #pragma unroll
        for (int i = 0; i < 9; ++i) {
            float4 v = kr[i];
            kv[4*i] = v.x; kv[4*i+1] = v.y; kv[4*i+2] = v.z; kv[4*i+3] = v.w;
        }
        #pragma unroll
        for (int dd = 0; dd < 36; ++dd) K_s[dd * 512 + tid] = kv[dd];
    }

    const float* Vbh = Vb + (size_t)bh * 512 * 36;
    const int dpv = l & 31, halfw = l >> 5;

    for (int p = 0; p < 3; ++p) {
        const int t0p = chunk * 96 + p * 32;
        __syncthreads();                       // K_s ready / prev pass done
        for (int idx = tid; idx < 32 * 36; idx += 512) {
            int r = idx & 31, dd = idx >> 5;
            Q_s[dd * 32 + r] = Qb[((size_t)bh * 1536 + t0p + r) * 36 + dd];
        }
        __syncthreads();

        // ---- QK^T: acc[4 rows][8 slots], slot j -> n = (j>>2)*256 + l*4 + (j&3)
        float acc[4][8];
        #pragma unroll
        for (int r = 0; r < 4; ++r)
            #pragma unroll
            for (int j = 0; j < 8; ++j) acc[r][j] = 0.f;

        #pragma unroll 6
        for (int dd = 0; dd < 36; ++dd) {
            float4 q  = FI4(&Q_s[dd * 32 + w4]);            // broadcast
            float4 ka = FI4(&K_s[dd * 512 + l * 4]);        // lane*16B, conflict-free
            float4 kb2 = FI4(&K_s[dd * 512 + 256 + l * 4]);
            float qv[4] = {q.x, q.y, q.z, q.w};
            float kv[8] = {ka.x, ka.y, ka.z, ka.w, kb2.x, kb2.y, kb2.z, kb2.w};
            #pragma unroll
            for (int r = 0; r < 4; ++r)
                #pragma unroll
                for (int j = 0; j < 8; ++j)
                    acc[r][j] = fmaf(qv[r], kv[j], acc[r][j]);
        }

        // ---- per row-pair: gumbel, sort-8, 16x (max-reduce, min-n, pop) + fused PV
        #pragma unroll
        for (int pr = 0; pr < 2; ++pr) {
            const int ta = t0p + w4 + pr * 2;
            const int tb = ta + 1;

            float sa[8], sb[8]; int na[8], nb[8];
            {
                const float* ua = un + ((size_t)bh * 1536 + ta) * 512;
                float4 u0 = FI4(&ua[l * 4]);
                float4 u1 = FI4(&ua[256 + l * 4]);
                sa[0] = fmaf(acc[pr*2][0], S6, gumbelf(u0.x));
                sa[1] = fmaf(acc[pr*2][1], S6, gumbelf(u0.y));
                sa[2] = fmaf(acc[pr*2][2], S6, gumbelf(u0.z));
                sa[3] = fmaf(acc[pr*2][3], S6, gumbelf(u0.w));
                sa[4] = fmaf(acc[pr*2][4], S6, gumbelf(u1.x));
                sa[5] = fmaf(acc[pr*2][5], S6, gumbelf(u1.y));
                sa[6] = fmaf(acc[pr*2][6], S6, gumbelf(u1.z));
                sa[7] = fmaf(acc[pr*2][7], S6, gumbelf(u1.w));
            }
            {
                const float* ub = un + ((size_t)bh * 1536 + tb) * 512;
                float4 u0 = FI4(&ub[l * 4]);
                float4 u1 = FI4(&ub[256 + l * 4]);
                sb[0] = fmaf(acc[pr*2+1][0], S6, gumbelf(u0.x));
                sb[1] = fmaf(acc[pr*2+1][1], S6, gumbelf(u0.y));
                sb[2] = fmaf(acc[pr*2+1][2], S6, gumbelf(u0.z));
                sb[3] = fmaf(acc[pr*2+1][3], S6, gumbelf(u0.w));
                sb[4] = fmaf(acc[pr*2+1][4], S6, gumbelf(u1.x));
                sb[5] = fmaf(acc[pr*2+1][5], S6, gumbelf(u1.y));
                sb[6] = fmaf(acc[pr*2+1][6], S6, gumbelf(u1.z));
                sb[7] = fmaf(acc[pr*2+1][7], S6, gumbelf(u1.w));
            }
            #pragma unroll
            for (int j = 0; j < 8; ++j) {
                na[j] = ((j >> 2) << 8) + l * 4 + (j & 3);
                nb[j] = na[j];
            }
            sort8(sa, na);
            sort8(sb, nb);

            float od = 0.f, od2 = 0.f;
            float m0a = 0.f, m0b = 0.f, ssa = 0.f, ssb = 0.f;

            #pragma unroll
            for (int k = 0; k < 16; ++k) {
                float ma = wave_max_bcast(sa[0]);
                unsigned ca = (sa[0] == ma) ? (unsigned)na[0] : 0xffffffffu;
                unsigned wa = wave_min_bcast_u32(ca);
                float mb = wave_max_bcast(sb[0]);
                unsigned cb = (sb[0] == mb) ? (unsigned)nb[0] : 0xffffffffu;
                unsigned wb = wave_min_bcast_u32(cb);
                if (k == 0) { m0a = ma; m0b = mb; }
                float ea = __expf(ma - m0a); ssa += ea;
                float eb = __expf(mb - m0b); ssb += eb;

                // fused PV: half 0 -> row a, half 1 -> row b
                unsigned wn = halfw ? wb : wa;
                float    ew = halfw ? eb : ea;
                const float* vr = Vbh + (size_t)wn * 36;
                od = fmaf(ew, vr[dpv], od);
                if (dpv < 4) od2 = fmaf(ew, vr[32 + dpv], od2);

                if (ca == wa) {   // pop head of row-a list (exactly one lane)
                    sa[0]=sa[1]; na[0]=na[1]; sa[1]=sa[2]; na[1]=na[2];
                    sa[2]=sa[3]; na[2]=na[3]; sa[3]=sa[4]; na[3]=na[4];
                    sa[4]=sa[5]; na[4]=na[5]; sa[5]=sa[6]; na[5]=na[6];
                    sa[6]=sa[7]; na[6]=na[7]; sa[7]=-INFINITY;
                }
                if (cb == wb) {
                    sb[0]=sb[1]; nb[0]=nb[1]; sb[1]=sb[2]; nb[1]=nb[2];
                    sb[2]=sb[3]; nb[2]=nb[3]; sb[3]=sb[4]; nb[3]=nb[4];
                    sb[4]=sb[5]; nb[4]=nb[5]; sb[5]=sb[6]; nb[5]=nb[6];
                    sb[6]=sb[7]; nb[6]=nb[7]; sb[7]=-INFINITY;
                }
            }

            float inv = 1.f / (halfw ? ssb : ssa);
            int   t   = halfw ? tb : ta;
            float* orow = att + ((size_t)b * 1536 + t) * 288 + h * 36;
            orow[dpv] = od * inv;
            if (dpv < 4) orow[32 + dpv] = od2 * inv;
        }
    }
}

// ---------------------------------------------------------------------------
extern "C" void kernel_launch(void* const* d_in, const int* in_sizes, int n_in,
                              void* d_out, int out_size, void* d_ws, size_t ws_size,
                              hipStream_t stream)
{
    (void)in_sizes; (void)n_in; (void)out_size; (void)ws_size;
    const float* x1      = (const float*)d_in[0];
    const float* x2      = (const float*)d_in[1];
    const float* x3      = (const float*)d_in[2];
    const float* xf      = (const float*)d_in[3];
    const float* emb     = (const float*)d_in[4];
    const float* un      = (const float*)d_in[5];
    const float* adaln_w = (const float*)d_in[6];
    const float* adaln_b = (const float*)d_in[7];
    const float* xfn_w   = (const float*)d_in[8];
    const float* xfn_b   = (const float*)d_in[9];
    const float* q_w     = (const float*)d_in[10];
    const float* q_b     = (const float*)d_in[11];
    const float* k_w     = (const float*)d_in[12];
    const float* k_b     = (const float*)d_in[13];
    const float* v_w     = (const float*)d_in[14];
    const float* v_b     = (const float*)d_in[15];
    const float* out_w   = (const float*)d_in[16];
    const float* out_b   = (const float*)d_in[17];
    float* out = (float*)d_out;

    float* ws   = (float*)d_ws;
    float* eo   = ws;                       // 16384
    float* xnq  = eo  + 16384;              // 6144*512
    float* xfn  = xnq + 6144 * 512;         // 16384*512
    float* Qb   = xfn + 16384 * 512;        // 32*1536*36
    float* Kb   = Qb  + 32 * 1536 * 36;     // 32*512*36
    float* Vb   = Kb  + 32 * 512 * 36;      // 32*512*36
    float* att  = Vb  + 32 * 512 * 36;      // 6144*288

    eo_kernel<<<4096, 256, 0, stream>>>(emb, adaln_w, adaln_b, xfn_w, xfn_b, eo);
    ln_kernel<<<22528, 256, 0, stream>>>(x1, x2, x3, xf, eo, xnq, xfn);
    gemm_kernel<<<48 * 5, 256, 0, stream>>>(0, xnq, q_w, nullptr, q_b, nullptr, Qb, nullptr, 5);
    gemm_kernel<<<128 * 2, 256, 0, stream>>>(1, xfn, k_w, v_w, k_b, v_b, Kb, Vb, 2);
    attn_kernel<<<512, 512, 0, stream>>>(Qb, Kb, Vb, un, att);
    gemm_kernel<<<48 * 8, 256, 0, stream>>>(2, att, out_w, nullptr, out_b, nullptr, out, nullptr, 8);
}

// Round 5
// 342.376 us; speedup vs baseline: 1.4995x; 1.1654x over previous
//
#include <hip/hip_runtime.h>
#include <math.h>

#define FI4(p) (*(const float4*)(p))

__device__ __forceinline__ float gumbelf(float u) {
    return -__logf(-__logf(u + 1e-9f) + 1e-9f);
}

template<int CTRL>
__device__ __forceinline__ int dppmov(int v) {
    return __builtin_amdgcn_update_dpp(v, v, CTRL, 0xF, 0xF, false);
}
// 64-lane sum; valid at lane 63, broadcast via readlane 63
__device__ __forceinline__ float wave_sum_bcast(float v) {
    v += __int_as_float(dppmov<0xB1>(__float_as_int(v)));   // quad_perm xor1
    v += __int_as_float(dppmov<0x4E>(__float_as_int(v)));   // quad_perm xor2
    v += __int_as_float(dppmov<0x141>(__float_as_int(v)));  // row_half_mirror
    v += __int_as_float(dppmov<0x140>(__float_as_int(v)));  // row_mirror
    v += __int_as_float(dppmov<0x142>(__float_as_int(v)));  // row_bcast15
    v += __int_as_float(dppmov<0x143>(__float_as_int(v)));  // row_bcast31
    return __int_as_float(__builtin_amdgcn_readlane(__float_as_int(v), 63));
}

// order-preserving f32 -> u32 (all finite values map > 0)
__device__ __forceinline__ unsigned ordkey(float f) {
    unsigned x = __float_as_uint(f);
    return x ^ ((unsigned)((int)x >> 31) | 0x80000000u);
}

// Exact top-16 membership over 512 wave-distributed keys (8 slots/lane).
// Binary search for T with #{u > T} == 16 (ballot+popcount, SALU-heavy).
// Non-early-exit happens only when u16 == u17 (exact f32 duplicate at the
// boundary): fill remaining picks by smallest n, n = (j>>2)*256 + lane*4 + (j&3).
__device__ __forceinline__ void select16(const unsigned* u, unsigned long long* sel)
{
    unsigned lo = 0u, hi = 0xffffffffu;
    while (hi - lo > 1u) {
        unsigned mid = lo + ((hi - lo) >> 1);
        unsigned long long mm[8];
        int cnt = 0;
        #pragma unroll
        for (int j = 0; j < 8; ++j) { mm[j] = __ballot(u[j] > mid); cnt += __popcll(mm[j]); }
        if (cnt == 16) {
            #pragma unroll
            for (int j = 0; j < 8; ++j) sel[j] = mm[j];
            return;
        }
        if (cnt > 16) lo = mid; else hi = mid;
    }
    // hi == u16 (== u17): strict-greater set + index-ordered tie fill
    unsigned long long eq[8];
    int mcnt = 0;
    #pragma unroll
    for (int j = 0; j < 8; ++j) {
        sel[j] = __ballot(u[j] > hi);
        eq[j]  = __ballot(u[j] == hi);
        mcnt += __popcll(sel[j]);
    }
    int r = 16 - mcnt;
    #pragma unroll
    for (int jhi = 0; jhi < 2; ++jhi) {
        if (r > 0) {
            unsigned long long any = eq[jhi*4] | eq[jhi*4+1] | eq[jhi*4+2] | eq[jhi*4+3];
            while (any && r > 0) {
                int lane = (int)__builtin_ctzll(any); any &= any - 1;
                #pragma unroll
                for (int jlo = 0; jlo < 4; ++jlo) {
                    int j2 = jhi * 4 + jlo;
                    if (r > 0 && ((eq[j2] >> lane) & 1ull)) { sel[j2] |= 1ull << lane; --r; }
                }
            }
        }
    }
}

// ---------------------------------------------------------------------------
// eo = silu(emb) @ W^T + b   for the 4 AdaLN linears (l=0..2 branches, l=3 xf)
// ---------------------------------------------------------------------------
__global__ __launch_bounds__(256) void eo_kernel(
    const float* __restrict__ emb,
    const float* __restrict__ adaln_w, const float* __restrict__ adaln_b,
    const float* __restrict__ xfn_w,  const float* __restrict__ xfn_b,
    float* __restrict__ eo)
{
    int wid  = blockIdx.x * 4 + (threadIdx.x >> 6);
    int lane = threadIdx.x & 63;
    int l = wid >> 12;
    int rem = wid & 4095;
    int b = rem >> 10;
    int o = rem & 1023;
    const float* wrow = (l < 3) ? (adaln_w + ((size_t)(l * 1024 + o)) * 512)
                                : (xfn_w + (size_t)o * 512);
    const float* erow = emb + b * 512;
    float acc = 0.f;
    for (int d = lane; d < 512; d += 64) {
        float e = erow[d];
        float se = e / (1.f + __expf(-e));   // silu
        acc = fmaf(se, wrow[d], acc);
    }
    #pragma unroll
    for (int off = 32; off; off >>= 1) acc += __shfl_xor(acc, off, 64);
    if (lane == 0) {
        float bias = (l < 3) ? adaln_b[l * 1024 + o] : xfn_b[o];
        eo[wid] = acc + bias;
    }
}

// ---------------------------------------------------------------------------
// LayerNorm (biased var) + modulation
// ---------------------------------------------------------------------------
__global__ __launch_bounds__(256) void ln_kernel(
    const float* __restrict__ x1, const float* __restrict__ x2,
    const float* __restrict__ x3, const float* __restrict__ xf,
    const float* __restrict__ eo,
    float* __restrict__ xnq, float* __restrict__ xfnb)
{
    int row = blockIdx.x;
    const float* src; const float* eorow; float* dst;
    if (row < 6144) {
        int l = row >> 11, idx = row & 2047, b = idx >> 9;
        const float* xp = (l == 0) ? x1 : (l == 1) ? x2 : x3;
        src = xp + (size_t)idx * 512;
        eorow = eo + (size_t)(l * 4 + b) * 1024;
        dst = xnq + (size_t)row * 512;
    } else {
        int rr = row - 6144; int b = rr >> 12;
        src = xf + (size_t)rr * 512;
        eorow = eo + (size_t)(12 + b) * 1024;
        dst = xfnb + (size_t)rr * 512;
    }
    int tid = threadIdx.x;
    float v0 = src[tid], v1 = src[tid + 256];
    float s = v0 + v1;
    float q = fmaf(v0, v0, v1 * v1);
    #pragma unroll
    for (int off = 32; off; off >>= 1) {
        s += __shfl_xor(s, off, 64);
        q += __shfl_xor(q, off, 64);
    }
    __shared__ float red[8];
    int wv = tid >> 6, lane = tid & 63;
    if (lane == 0) { red[wv] = s; red[4 + wv] = q; }
    __syncthreads();
    s = red[0] + red[1] + red[2] + red[3];
    q = red[4] + red[5] + red[6] + red[7];
    float mu  = s * (1.f / 512.f);
    float var = q * (1.f / 512.f) - mu * mu;
    float rs  = 1.f / sqrtf(var + 1e-6f);
    dst[tid]       = (v0 - mu) * rs * (1.f + eorow[tid])       + eorow[512 + tid];
    dst[tid + 256] = (v1 - mu) * rs * (1.f + eorow[tid + 256]) + eorow[768 + tid];
}

// ---------------------------------------------------------------------------
// Generic f32 GEMM  C = A * W^T (+bias), tile 64x64, BK=32, micro 4x4
// grid doubled vs 128-row tiles -> 2-3 blocks/CU
// ---------------------------------------------------------------------------
__global__ __launch_bounds__(256) void gemm_kernel(
    int mode,
    const float* __restrict__ A,
    const float* __restrict__ W0, const float* __restrict__ W1,
    const float* __restrict__ B0, const float* __restrict__ B1,
    float* __restrict__ C0, float* __restrict__ C1,
    int NB)
{
    __shared__ float A_s[32][68];
    __shared__ float W_s[32][68];

    const int tid = threadIdx.x;
    const int mb = blockIdx.x / NB, nb = blockIdx.x % NB;
    const int row0 = mb * 64, o0 = nb * 64;
    const int Kdim = (mode == 2) ? 288 : 512;
    const int OUTS = (mode == 0) ? 288 : (mode == 1) ? 72 : 512;

    int l = 0, h = 0;
    if (mode == 1) h = (row0 >> 9) & 7;
    else           l = row0 >> 11;

    size_t arow0;
    if (mode == 2) {
        int rb = row0 & 2047; int bb = rb >> 9; int tb = row0 & 511;
        arow0 = (size_t)bb * 1536 + (size_t)l * 512 + tb;
    } else {
        arow0 = (size_t)row0;
    }

    const int lk = tid & 31, lr = tid >> 5;
    float acc[4][4];
    #pragma unroll
    for (int i = 0; i < 4; ++i)
        #pragma unroll
        for (int j = 0; j < 4; ++j) acc[i][j] = 0.f;

    for (int kt = 0; kt < Kdim; kt += 32) {
        #pragma unroll
        for (int i = 0; i < 8; ++i) {
            int m = lr + 8 * i;
            A_s[lk][m] = A[(arow0 + m) * Kdim + kt + lk];
        }
        #pragma unroll
        for (int i = 0; i < 8; ++i) {
            int o = lr + 8 * i;
            int og = o0 + o;
            float val = 0.f;
            if (og < OUTS) {
                const float* wr;
                if (mode == 0)      wr = W0 + ((size_t)(l * 288 + og)) * 512;
                else if (mode == 1) wr = (og < 36) ? W0 + ((size_t)(h * 36 + og)) * 512
                                                   : W1 + ((size_t)(h * 36 + og - 36)) * 512;
                else                wr = W0 + ((size_t)(l * 512 + og)) * 288;
                val = wr[kt + lk];
            }
            W_s[lk][o] = val;
        }
        __syncthreads();
        #pragma unroll
        for (int kk = 0; kk < 32; ++kk) {
            float4 a = FI4(&A_s[kk][4 * (tid & 15)]);
            float4 w = FI4(&W_s[kk][4 * (tid >> 4)]);
            float av[4] = {a.x, a.y, a.z, a.w};
            float wv[4] = {w.x, w.y, w.z, w.w};
            #pragma unroll
            for (int i = 0; i < 4; ++i)
                #pragma unroll
                for (int j = 0; j < 4; ++j)
                    acc[i][j] = fmaf(av[i], wv[j], acc[i][j]);
        }
        __syncthreads();
    }

    const int tm = tid & 15, tn = tid >> 4;
    const int cb = o0 + 4 * tn;
    if (cb >= OUTS) return;

    #pragma unroll
    for (int i = 0; i < 4; ++i) {
        int r = row0 + 4 * tm + i;
        float4 v;
        if (mode == 0) {
            int rb = r & 2047; int bb = rb >> 9; int t = rb & 511;
            int tgl = l * 512 + t;
            int hh = cb / 36; int hd = cb - hh * 36;
            v.x = acc[i][0] + B0[l * 288 + cb + 0];
            v.y = acc[i][1] + B0[l * 288 + cb + 1];
            v.z = acc[i][2] + B0[l * 288 + cb + 2];
            v.w = acc[i][3] + B0[l * 288 + cb + 3];
            *(float4*)&C0[(((size_t)bb * 8 + hh) * 1536 + tgl) * 36 + hd] = v;
        } else if (mode == 1) {
            int bb = r >> 12; int nn = r & 511;
            if (cb < 36) {
                v.x = acc[i][0] + B0[h * 36 + cb + 0];
                v.y = acc[i][1] + B0[h * 36 + cb + 1];
                v.z = acc[i][2] + B0[h * 36 + cb + 2];
                v.w = acc[i][3] + B0[h * 36 + cb + 3];
                *(float4*)&C0[(((size_t)bb * 8 + h) * 512 + nn) * 36 + cb] = v;
            } else {
                int c2 = cb - 36;
                v.x = acc[i][0] + B1[h * 36 + c2 + 0];
                v.y = acc[i][1] + B1[h * 36 + c2 + 1];
                v.z = acc[i][2] + B1[h * 36 + c2 + 2];
                v.w = acc[i][3] + B1[h * 36 + c2 + 3];
                *(float4*)&C1[(((size_t)bb * 8 + h) * 512 + nn) * 36 + c2] = v;
            }
        } else {
            int rb = r & 2047; int bb = rb >> 9; int t = rb & 511;
            v.x = acc[i][0] + B0[l * 512 + cb + 0];
            v.y = acc[i][1] + B0[l * 512 + cb + 1];
            v.z = acc[i][2] + B0[l * 512 + cb + 2];
            v.w = acc[i][3] + B0[l * 512 + cb + 3];
            *(float4*)&C0[(size_t)l * 1048576 + ((size_t)bb * 512 + t) * 512 + cb] = v;
        }
    }
}

// ---------------------------------------------------------------------------
// Attention v3: K in LDS, Q staged 32 rows/pass, QK^T in registers.
// Top-16 via ballot-bisection threshold (select16), softmax weights via raw
// exp + DPP wave-sum, PV gather with half-wave 0 -> row a, half 1 -> row b.
// ---------------------------------------------------------------------------
__global__ __launch_bounds__(512, 4) void attn_kernel(
    const float* __restrict__ Qb, const float* __restrict__ Kb,
    const float* __restrict__ Vb, const float* __restrict__ un,
    float* __restrict__ att)
{
    __shared__ float K_s[36 * 512];
    __shared__ float Q_s[36 * 32];

    const int tid = threadIdx.x;
    const int bh = blockIdx.x >> 4;
    const int chunk = blockIdx.x & 15;
    const int b = bh >> 3, h = bh & 7;
    const int l = tid & 63;
    const int w4 = (tid >> 6) * 4;          // wave's 4-row base within the 32-row pass
    const int dpv = l & 31, halfw = l >> 5;
    const float S6 = 1.0f / 6.0f;

    // ---- stage K: thread t handles K row t -> K_s[d][t] (conflict-free writes)
    {
        const float4* kr = (const float4*)(Kb + ((size_t)bh * 512 + tid) * 36);
        float kv[36];
        #pragma unroll
        for (int i = 0; i < 9; ++i) {
            float4 v = kr[i];
            kv[4*i] = v.x; kv[4*i+1] = v.y; kv[4*i+2] = v.z; kv[4*i+3] = v.w;
        }
        #pragma unroll
        for (int dd = 0; dd < 36; ++dd) K_s[dd * 512 + tid] = kv[dd];
    }

    const float* Vbh = Vb + (size_t)bh * 512 * 36;

    for (int p = 0; p < 3; ++p) {
        const int t0p = chunk * 96 + p * 32;
        __syncthreads();                       // K_s ready / prev pass done
        for (int idx = tid; idx < 32 * 36; idx += 512) {
            int r = idx & 31, dd = idx >> 5;
            Q_s[dd * 32 + r] = Qb[((size_t)bh * 1536 + t0p + r) * 36 + dd];
        }
        __syncthreads();

        // ---- QK^T: acc[4 rows][8 slots], slot j -> n = (j>>2)*256 + l*4 + (j&3)
        float acc[4][8];
        #pragma unroll
        for (int r = 0; r < 4; ++r)
            #pragma unroll
            for (int j = 0; j < 8; ++j) acc[r][j] = 0.f;

        #pragma unroll 6
        for (int dd = 0; dd < 36; ++dd) {
            float4 q   = FI4(&Q_s[dd * 32 + w4]);           // broadcast
            float4 ka  = FI4(&K_s[dd * 512 + l * 4]);       // lane*16B, conflict-free
            float4 kb2 = FI4(&K_s[dd * 512 + 256 + l * 4]);
            float qv[4] = {q.x, q.y, q.z, q.w};
            float kv[8] = {ka.x, ka.y, ka.z, ka.w, kb2.x, kb2.y, kb2.z, kb2.w};
            #pragma unroll
            for (int r = 0; r < 4; ++r)
                #pragma unroll
                for (int j = 0; j < 8; ++j)
                    acc[r][j] = fmaf(qv[r], kv[j], acc[r][j]);
        }

        // ---- per row-pair: gumbel, threshold select, fused softmax+PV
        #pragma unroll
        for (int pr = 0; pr < 2; ++pr) {
            const int ta = t0p + w4 + pr * 2;

            float sa[8], sb[8];
            {
                const float* ua = un + ((size_t)bh * 1536 + ta) * 512;
                float4 u0 = FI4(&ua[l * 4]);
                float4 u1 = FI4(&ua[256 + l * 4]);
                sa[0] = fmaf(acc[pr*2][0], S6, gumbelf(u0.x));
                sa[1] = fmaf(acc[pr*2][1], S6, gumbelf(u0.y));
                sa[2] = fmaf(acc[pr*2][2], S6, gumbelf(u0.z));
                sa[3] = fmaf(acc[pr*2][3], S6, gumbelf(u0.w));
                sa[4] = fmaf(acc[pr*2][4], S6, gumbelf(u1.x));
                sa[5] = fmaf(acc[pr*2][5], S6, gumbelf(u1.y));
                sa[6] = fmaf(acc[pr*2][6], S6, gumbelf(u1.z));
                sa[7] = fmaf(acc[pr*2][7], S6, gumbelf(u1.w));
            }
            {
                const float* ub = un + ((size_t)bh * 1536 + ta + 1) * 512;
                float4 u0 = FI4(&ub[l * 4]);
                float4 u1 = FI4(&ub[256 + l * 4]);
                sb[0] = fmaf(acc[pr*2+1][0], S6, gumbelf(u0.x));
                sb[1] = fmaf(acc[pr*2+1][1], S6, gumbelf(u0.y));
                sb[2] = fmaf(acc[pr*2+1][2], S6, gumbelf(u0.z));
                sb[3] = fmaf(acc[pr*2+1][3], S6, gumbelf(u0.w));
                sb[4] = fmaf(acc[pr*2+1][4], S6, gumbelf(u1.x));
                sb[5] = fmaf(acc[pr*2+1][5], S6, gumbelf(u1.y));
                sb[6] = fmaf(acc[pr*2+1][6], S6, gumbelf(u1.z));
                sb[7] = fmaf(acc[pr*2+1][7], S6, gumbelf(u1.w));
            }

            unsigned ua32[8], ub32[8];
            #pragma unroll
            for (int j = 0; j < 8; ++j) { ua32[j] = ordkey(sa[j]); ub32[j] = ordkey(sb[j]); }

            unsigned long long selA[8], selB[8];
            select16(ua32, selA);
            select16(ub32, selB);

            // weights: raw exp (logits <= ~20, no overflow; ratio == softmax)
            float eA[8], eB[8], psA = 0.f, psB = 0.f;
            #pragma unroll
            for (int j = 0; j < 8; ++j) {
                float exa = __expf(sa[j]);
                float exb = __expf(sb[j]);
                eA[j] = ((selA[j] >> l) & 1ull) ? exa : 0.f;
                eB[j] = ((selB[j] >> l) & 1ull) ? exb : 0.f;
                psA += eA[j]; psB += eB[j];
            }
            float sumA = wave_sum_bcast(psA);
            float sumB = wave_sum_bcast(psB);

            // PV gather: half-wave 0 accumulates row a, half-wave 1 row b
            float od = 0.f, od2 = 0.f;
            #pragma unroll
            for (int j = 0; j < 8; ++j) {
                unsigned long long ma = selA[j], mb = selB[j];
                const int nbase = ((j >> 2) << 8) + (j & 3);
                while (ma | mb) {
                    int la = ma ? (int)__builtin_ctzll(ma) : 0;
                    int lb = mb ? (int)__builtin_ctzll(mb) : 0;
                    float ewa = __int_as_float(__builtin_amdgcn_readlane(__float_as_int(eA[j]), la));
                    float ewb = __int_as_float(__builtin_amdgcn_readlane(__float_as_int(eB[j]), lb));
                    ewa = ma ? ewa : 0.f;
                    ewb = mb ? ewb : 0.f;
                    int na  = nbase + la * 4;
                    int nb2 = nbase + lb * 4;
                    int nsel = halfw ? nb2 : na;
                    float ew = halfw ? ewb : ewa;
                    const float* vr = Vbh + (size_t)nsel * 36;
                    od = fmaf(ew, vr[dpv], od);
                    if (dpv < 4) od2 = fmaf(ew, vr[32 + dpv], od2);
                    ma = ma ? (ma & (ma - 1)) : 0ull;
                    mb = mb ? (mb & (mb - 1)) : 0ull;
                }
            }

            float invs = 1.0f / (halfw ? sumB : sumA);
            int t = ta + halfw;
            float* orow = att + ((size_t)b * 1536 + t) * 288 + h * 36;
            orow[dpv] = od * invs;
            if (dpv < 4) orow[32 + dpv] = od2 * invs;
        }
    }
}

// ---------------------------------------------------------------------------
extern "C" void kernel_launch(void* const* d_in, const int* in_sizes, int n_in,
                              void* d_out, int out_size, void* d_ws, size_t ws_size,
                              hipStream_t stream)
{
    (void)in_sizes; (void)n_in; (void)out_size; (void)ws_size;
    const float* x1      = (const float*)d_in[0];
    const float* x2      = (const float*)d_in[1];
    const float* x3      = (const float*)d_in[2];
    const float* xf      = (const float*)d_in[3];
    const float* emb     = (const float*)d_in[4];
    const float* un      = (const float*)d_in[5];
    const float* adaln_w = (const float*)d_in[6];
    const float* adaln_b = (const float*)d_in[7];
    const float* xfn_w   = (const float*)d_in[8];
    const float* xfn_b   = (const float*)d_in[9];
    const float* q_w     = (const float*)d_in[10];
    const float* q_b     = (const float*)d_in[11];
    const float* k_w     = (const float*)d_in[12];
    const float* k_b     = (const float*)d_in[13];
    const float* v_w     = (const float*)d_in[14];
    const float* v_b     = (const float*)d_in[15];
    const float* out_w   = (const float*)d_in[16];
    const float* out_b   = (const float*)d_in[17];
    float* out = (float*)d_out;

    float* ws   = (float*)d_ws;
    float* eo   = ws;                       // 16384
    float* xnq  = eo  + 16384;              // 6144*512
    float* xfn  = xnq + 6144 * 512;         // 16384*512
    float* Qb   = xfn + 16384 * 512;        // 32*1536*36
    float* Kb   = Qb  + 32 * 1536 * 36;     // 32*512*36
    float* Vb   = Kb  + 32 * 512 * 36;      // 32*512*36
    float* att  = Vb  + 32 * 512 * 36;      // 6144*288

    eo_kernel<<<4096, 256, 0, stream>>>(emb, adaln_w, adaln_b, xfn_w, xfn_b, eo);
    ln_kernel<<<22528, 256, 0, stream>>>(x1, x2, x3, xf, eo, xnq, xfn);
    gemm_kernel<<<96 * 5, 256, 0, stream>>>(0, xnq, q_w, nullptr, q_b, nullptr, Qb, nullptr, 5);
    gemm_kernel<<<256 * 2, 256, 0, stream>>>(1, xfn, k_w, v_w, k_b, v_b, Kb, Vb, 2);
    attn_kernel<<<512, 512, 0, stream>>>(Qb, Kb, Vb, un, att);
    gemm_kernel<<<96 * 8, 256, 0, stream>>>(2, att, out_w, nullptr, out_b, nullptr, out, nullptr, 8);
}

// Round 9
// 216.668 us; speedup vs baseline: 2.3695x; 1.5802x over previous
//
#include <hip/hip_runtime.h>
#include <math.h>

#define FI4(p) (*(const float4*)(p))

typedef _Float16 half8 __attribute__((ext_vector_type(8)));
typedef float f32x4 __attribute__((ext_vector_type(4)));

__device__ __forceinline__ float gumbelf(float u) {
    return -__logf(-__logf(u + 1e-9f) + 1e-9f);
}

template<int CTRL>
__device__ __forceinline__ int dppmov(int v) {
    return __builtin_amdgcn_update_dpp(v, v, CTRL, 0xF, 0xF, false);
}
// 64-lane max, broadcast via readlane 63
__device__ __forceinline__ float wave_max_bcast(float v) {
    v = fmaxf(v, __int_as_float(dppmov<0xB1>(__float_as_int(v))));
    v = fmaxf(v, __int_as_float(dppmov<0x4E>(__float_as_int(v))));
    v = fmaxf(v, __int_as_float(dppmov<0x141>(__float_as_int(v))));
    v = fmaxf(v, __int_as_float(dppmov<0x140>(__float_as_int(v))));
    v = fmaxf(v, __int_as_float(dppmov<0x142>(__float_as_int(v))));
    v = fmaxf(v, __int_as_float(dppmov<0x143>(__float_as_int(v))));
    return __int_as_float(__builtin_amdgcn_readlane(__float_as_int(v), 63));
}
__device__ __forceinline__ float wave_sum_bcast(float v) {
    v += __int_as_float(dppmov<0xB1>(__float_as_int(v)));
    v += __int_as_float(dppmov<0x4E>(__float_as_int(v)));
    v += __int_as_float(dppmov<0x141>(__float_as_int(v)));
    v += __int_as_float(dppmov<0x140>(__float_as_int(v)));
    v += __int_as_float(dppmov<0x142>(__float_as_int(v)));
    v += __int_as_float(dppmov<0x143>(__float_as_int(v)));
    return __int_as_float(__builtin_amdgcn_readlane(__float_as_int(v), 63));
}

__device__ __forceinline__ unsigned ordkey(float f) {
    unsigned x = __float_as_uint(f);
    return x ^ ((unsigned)((int)x >> 31) | 0x80000000u);
}

__device__ __forceinline__ int mbcnt64(unsigned long long m) {
    return __builtin_amdgcn_mbcnt_hi((unsigned)(m >> 32),
           __builtin_amdgcn_mbcnt_lo((unsigned)m, 0));
}

__device__ __forceinline__ void copy8(unsigned long long* dst, const unsigned long long* src) {
    #pragma unroll
    for (int j = 0; j < 8; ++j) dst[j] = src[j];
}

// Exact top-16 membership over 512 wave-distributed keys (8 slots/lane).
__device__ __forceinline__ void select16(const unsigned* u, unsigned long long* sel,
                                         unsigned lo0, unsigned hi0)
{
    unsigned lo = lo0, hi = hi0;
    {
        unsigned long long mm[8];
        int cnt = 0;
        #pragma unroll
        for (int j = 0; j < 8; ++j) { mm[j] = __ballot(u[j] > lo); cnt += __popcll(mm[j]); }
        if (cnt == 16) { copy8(sel, mm); return; }
        if (cnt < 16) lo = 0u;   // ordkey(finite) > 0 => cnt(>0) = 512 > 16
    }
    while (hi - lo > 1u) {
        unsigned mid = lo + ((hi - lo) >> 1);
        unsigned long long mm[8];
        int cnt = 0;
        #pragma unroll
        for (int j = 0; j < 8; ++j) { mm[j] = __ballot(u[j] > mid); cnt += __popcll(mm[j]); }
        if (cnt == 16) { copy8(sel, mm); return; }
        if (cnt > 16) lo = mid; else hi = mid;
    }
    // u16 == u17 == hi: strict-greater + smallest-n tie fill
    unsigned long long eq[8];
    int mcnt = 0;
    #pragma unroll
    for (int j = 0; j < 8; ++j) {
        sel[j] = __ballot(u[j] > hi);
        eq[j]  = __ballot(u[j] == hi);
        mcnt += __popcll(sel[j]);
    }
    int r = 16 - mcnt;
    #pragma unroll
    for (int jhi = 0; jhi < 2; ++jhi) {
        if (r > 0) {
            unsigned long long any = eq[jhi*4] | eq[jhi*4+1] | eq[jhi*4+2] | eq[jhi*4+3];
            while (any && r > 0) {
                int lane = (int)__builtin_ctzll(any); any &= any - 1;
                #pragma unroll
                for (int jlo = 0; jlo < 4; ++jlo) {
                    int j2 = jhi * 4 + jlo;
                    if (r > 0 && ((eq[j2] >> lane) & 1ull)) { sel[j2] |= 1ull << lane; --r; }
                }
            }
        }
    }
}

// ---------------------------------------------------------------------------
// weights: q_w,k_w -> fp16 hi+lo split; v_w,out_w -> fp16 single
// ---------------------------------------------------------------------------
__global__ __launch_bounds__(256) void convw_kernel(
    const float* __restrict__ q_w, const float* __restrict__ k_w,
    const float* __restrict__ v_w, const float* __restrict__ out_w,
    _Float16* __restrict__ qwh, _Float16* __restrict__ qwl,
    _Float16* __restrict__ kwh, _Float16* __restrict__ kwl,
    _Float16* __restrict__ vw16, _Float16* __restrict__ ow16)
{
    int idx = blockIdx.x * 256 + threadIdx.x;
    if (idx < 442368) {
        float x = q_w[idx];
        _Float16 hi = (_Float16)x;
        qwh[idx] = hi; qwl[idx] = (_Float16)(x - (float)hi);
    } else if (idx < 442368 + 147456) {
        int i = idx - 442368;
        float x = k_w[i];
        _Float16 hi = (_Float16)x;
        kwh[i] = hi; kwl[i] = (_Float16)(x - (float)hi);
    } else if (idx < 442368 + 294912) {
        int i = idx - 442368 - 147456;
        vw16[i] = (_Float16)v_w[i];
    } else {
        int i = idx - 442368 - 294912;
        ow16[i] = (_Float16)out_w[i];
    }
}

// ---------------------------------------------------------------------------
// eo = silu(emb) @ W^T + b
// ---------------------------------------------------------------------------
__global__ __launch_bounds__(256) void eo_kernel(
    const float* __restrict__ emb,
    const float* __restrict__ adaln_w, const float* __restrict__ adaln_b,
    const float* __restrict__ xfn_w,  const float* __restrict__ xfn_b,
    float* __restrict__ eo)
{
    int wid  = blockIdx.x * 4 + (threadIdx.x >> 6);
    int lane = threadIdx.x & 63;
    int l = wid >> 12;
    int rem = wid & 4095;
    int b = rem >> 10;
    int o = rem & 1023;
    const float* wrow = (l < 3) ? (adaln_w + ((size_t)(l * 1024 + o)) * 512)
                                : (xfn_w + (size_t)o * 512);
    const float* erow = emb + b * 512;
    float acc = 0.f;
    for (int d = lane; d < 512; d += 64) {
        float e = erow[d];
        float se = e / (1.f + __expf(-e));
        acc = fmaf(se, wrow[d], acc);
    }
    #pragma unroll
    for (int off = 32; off; off >>= 1) acc += __shfl_xor(acc, off, 64);
    if (lane == 0) {
        float bias = (l < 3) ? adaln_b[l * 1024 + o] : xfn_b[o];
        eo[wid] = acc + bias;
    }
}

// ---------------------------------------------------------------------------
// LayerNorm + modulation -> fp16 hi+lo planes
// ---------------------------------------------------------------------------
__global__ __launch_bounds__(256) void ln_kernel(
    const float* __restrict__ x1, const float* __restrict__ x2,
    const float* __restrict__ x3, const float* __restrict__ xf,
    const float* __restrict__ eo,
    _Float16* __restrict__ xnqh, _Float16* __restrict__ xnql,
    _Float16* __restrict__ xfnh, _Float16* __restrict__ xfnl)
{
    int row = blockIdx.x;
    const float* src; const float* eorow; _Float16* dh; _Float16* dl;
    if (row < 6144) {
        int l = row >> 11, idx = row & 2047, b = idx >> 9;
        const float* xp = (l == 0) ? x1 : (l == 1) ? x2 : x3;
        src = xp + (size_t)idx * 512;
        eorow = eo + (size_t)(l * 4 + b) * 1024;
        dh = xnqh + (size_t)row * 512;
        dl = xnql + (size_t)row * 512;
    } else {
        int rr = row - 6144; int b = rr >> 12;
        src = xf + (size_t)rr * 512;
        eorow = eo + (size_t)(12 + b) * 1024;
        dh = xfnh + (size_t)rr * 512;
        dl = xfnl + (size_t)rr * 512;
    }
    int tid = threadIdx.x;
    float v0 = src[tid], v1 = src[tid + 256];
    float s = v0 + v1;
    float q = fmaf(v0, v0, v1 * v1);
    #pragma unroll
    for (int off = 32; off; off >>= 1) {
        s += __shfl_xor(s, off, 64);
        q += __shfl_xor(q, off, 64);
    }
    __shared__ float red[8];
    int wv = tid >> 6, lane = tid & 63;
    if (lane == 0) { red[wv] = s; red[4 + wv] = q; }
    __syncthreads();
    s = red[0] + red[1] + red[2] + red[3];
    q = red[4] + red[5] + red[6] + red[7];
    float mu  = s * (1.f / 512.f);
    float var = q * (1.f / 512.f) - mu * mu;
    float rs  = 1.f / sqrtf(var + 1e-6f);
    float r0 = (v0 - mu) * rs * (1.f + eorow[tid])       + eorow[512 + tid];
    float r1 = (v1 - mu) * rs * (1.f + eorow[tid + 256]) + eorow[768 + tid];
    _Float16 h0 = (_Float16)r0, h1 = (_Float16)r1;
    dh[tid]       = h0;  dl[tid]       = (_Float16)(r0 - (float)h0);
    dh[tid + 256] = h1;  dl[tid + 256] = (_Float16)(r1 - (float)h1);
}

// ---------------------------------------------------------------------------
// fp16 MFMA GEMM, LDS-free, per-wave 32 x (NF*16) tile.
// MODE 0: Q-proj  SPLIT  (xnq 6144x512 @ qw -> Qb [bh][1536][36])
// MODE 1: K-proj  SPLIT  (xfn 16384x512 @ kw -> Kt [bh][36][512] transposed)
// MODE 2: V-proj  single (xfn 16384x512 @ vw -> Vb [bh][512][36])
// MODE 3: out-proj single (att16 [b][1536][288] @ ow -> d_out, A-rows remapped)
// SPLIT: acc = Ah@Wh + Ah@Wl + Al@Wh  (fp16 two-term; f32-grade result)
// ---------------------------------------------------------------------------
template<int NF, int MODE>
__global__ __launch_bounds__(256) void gemm16_kernel(
    const _Float16* __restrict__ Ah, const _Float16* __restrict__ Al,
    const _Float16* __restrict__ Wh, const _Float16* __restrict__ Wl,
    const float* __restrict__ bias,
    float* __restrict__ O0)
{
    constexpr bool SPLIT = (MODE == 0 || MODE == 1);
    const int Kd = (MODE == 3) ? 288 : 512;
    const int NT = (MODE == 0) ? 6 : (MODE == 3) ? 8 : 1;
    const int gw = blockIdx.x * 4 + (threadIdx.x >> 6);
    const int l  = threadIdx.x & 63;
    const int mt = gw / NT, nt = gw - mt * NT;
    const int row0 = mt * 32;
    const int col0 = nt * (NF * 16);
    const int lr = l & 15, lk = (l >> 4) * 8;

    int lsel = 0, h = 0;
    if (MODE == 0)                 { lsel = row0 >> 11; }
    else if (MODE == 1 || MODE == 2) { h = (row0 >> 9) & 7; }
    else                           { lsel = row0 >> 11; }

    // A-row base: MODE 3's att16 is [b][l*512+t][288]; logical row
    // r = l*2048 + b*512 + t -> memory row b*1536 + l*512 + t.
    size_t arow0;
    if (MODE == 3) {
        int rb = row0 & 2047, bb = rb >> 9, t0 = rb & 511;
        arow0 = (size_t)bb * 1536 + (size_t)lsel * 512 + t0;
    } else {
        arow0 = (size_t)row0;
    }

    const _Float16* aph = Ah + (arow0 + lr) * Kd + lk;
    const _Float16* apl = SPLIT ? (Al + (arow0 + lr) * Kd + lk) : nullptr;

    const _Float16* bph[NF];
    const _Float16* bpl[NF];
    #pragma unroll
    for (int f = 0; f < NF; ++f) {
        int c = col0 + f * 16 + lr;
        int wr;
        if (MODE == 0)      wr = lsel * 288 + c;
        else if (MODE == 3) wr = lsel * 512 + c;
        else                wr = h * 36 + (c < 36 ? c : 0);   // clamp; write masked
        bph[f] = Wh + (size_t)wr * Kd + lk;
        if (SPLIT) bpl[f] = Wl + (size_t)wr * Kd + lk;
    }

    f32x4 acc[2][NF];
    #pragma unroll
    for (int mi = 0; mi < 2; ++mi)
        #pragma unroll
        for (int f = 0; f < NF; ++f) acc[mi][f] = (f32x4){0.f, 0.f, 0.f, 0.f};

    for (int kk = 0; kk < Kd; kk += 32) {
        half8 a0h = *(const half8*)(aph + kk);
        half8 a1h = *(const half8*)(aph + (size_t)16 * Kd + kk);
        half8 a0l, a1l;
        if constexpr (SPLIT) {
            a0l = *(const half8*)(apl + kk);
            a1l = *(const half8*)(apl + (size_t)16 * Kd + kk);
        }
        #pragma unroll
        for (int f = 0; f < NF; ++f) {
            half8 bh_ = *(const half8*)(bph[f] + kk);
            acc[0][f] = __builtin_amdgcn_mfma_f32_16x16x32_f16(a0h, bh_, acc[0][f], 0, 0, 0);
            acc[1][f] = __builtin_amdgcn_mfma_f32_16x16x32_f16(a1h, bh_, acc[1][f], 0, 0, 0);
            if constexpr (SPLIT) {
                half8 bl_ = *(const half8*)(bpl[f] + kk);
                acc[0][f] = __builtin_amdgcn_mfma_f32_16x16x32_f16(a0h, bl_, acc[0][f], 0, 0, 0);
                acc[1][f] = __builtin_amdgcn_mfma_f32_16x16x32_f16(a1h, bl_, acc[1][f], 0, 0, 0);
                acc[0][f] = __builtin_amdgcn_mfma_f32_16x16x32_f16(a0l, bh_, acc[0][f], 0, 0, 0);
                acc[1][f] = __builtin_amdgcn_mfma_f32_16x16x32_f16(a1l, bh_, acc[1][f], 0, 0, 0);
            }
        }
    }

    // epilogue: D row = (l>>4)*4 + j, col = l&15
    #pragma unroll
    for (int mi = 0; mi < 2; ++mi) {
        int rbase = row0 + mi * 16 + (l >> 4) * 4;
        #pragma unroll
        for (int f = 0; f < NF; ++f) {
            int c = col0 + f * 16 + (l & 15);
            if (MODE == 0) {
                int hh = c / 36, hd = c - hh * 36;
                float bz = bias[lsel * 288 + c];
                #pragma unroll
                for (int j = 0; j < 4; ++j) {
                    int r = rbase + j;
                    int rb = r & 2047, bb2 = rb >> 9, t = rb & 511;
                    O0[(((size_t)bb2 * 8 + hh) * 1536 + lsel * 512 + t) * 36 + hd]
                        = acc[mi][f][j] + bz;
                }
            } else if (MODE == 1) {
                if (c < 36) {
                    int bb2 = row0 >> 12;
                    int n0 = rbase & 511;
                    float bz = bias[h * 36 + c];
                    float4 v4;
                    v4.x = acc[mi][f][0] + bz; v4.y = acc[mi][f][1] + bz;
                    v4.z = acc[mi][f][2] + bz; v4.w = acc[mi][f][3] + bz;
                    *(float4*)&O0[(((size_t)bb2 * 8 + h) * 36 + c) * 512 + n0] = v4;
                }
            } else if (MODE == 2) {
                if (c < 36) {
                    int bb2 = row0 >> 12;
                    int n0 = rbase & 511;
                    float bz = bias[h * 36 + c];
                    #pragma unroll
                    for (int j = 0; j < 4; ++j)
                        O0[(((size_t)bb2 * 8 + h) * 512 + n0 + j) * 36 + c]
                            = acc[mi][f][j] + bz;
                }
            } else {
                float bz = bias[lsel * 512 + c];
                #pragma unroll
                for (int j = 0; j < 4; ++j) {
                    int r = rbase + j;
                    int rb = r & 2047, bb2 = rb >> 9, t = rb & 511;
                    O0[(size_t)lsel * 1048576 + ((size_t)bb2 * 512 + t) * 512 + c]
                        = acc[mi][f][j] + bz;
                }
            }
        }
    }
}

// ---------------------------------------------------------------------------
// Attention: grid 32bh x 48 chunks, 512 thr, one 32-row pass per block.
// Kt/Vb read from global (L2-hot); select16 bisection; PV via ballot-rank
// LDS compaction + fixed 16-iter gather. Writes att16 fp16 [b][1536][288].
// ---------------------------------------------------------------------------
__global__ __launch_bounds__(512, 4) void attn_kernel(
    const float* __restrict__ Qb, const float* __restrict__ Kt,
    const float* __restrict__ Vb, const float* __restrict__ un,
    _Float16* __restrict__ att16)
{
    __shared__ float Q_s[36 * 32];
    __shared__ float CmpW[8][2][2][16];
    __shared__ int   CmpN[8][2][2][16];

    const int tid = threadIdx.x;
    const int bh = blockIdx.x / 48;
    const int chunk = blockIdx.x - bh * 48;
    const int t0p = chunk * 32;
    const int b = bh >> 3, h = bh & 7;
    const int l = tid & 63;
    const int wv = tid >> 6;
    const int w4 = wv * 4;
    const int dpv = l & 31, halfw = l >> 5;
    const float S6 = 1.0f / 6.0f;

    for (int idx = tid; idx < 32 * 36; idx += 512) {
        int r = idx & 31, dd = idx >> 5;
        Q_s[dd * 32 + r] = Qb[((size_t)bh * 1536 + t0p + r) * 36 + dd];
    }
    __syncthreads();

    const float* Ktbh = Kt + (size_t)bh * 18432;
    const float* Vbh  = Vb + (size_t)bh * 18432;

    // QK^T: acc[4 rows][8 slots], slot j -> n = (j>>2)*256 + l*4 + (j&3)
    float acc[4][8];
    #pragma unroll
    for (int r = 0; r < 4; ++r)
        #pragma unroll
        for (int j = 0; j < 8; ++j) acc[r][j] = 0.f;

    #pragma unroll 6
    for (int dd = 0; dd < 36; ++dd) {
        float4 q   = FI4(&Q_s[dd * 32 + w4]);
        const float* ktr = Ktbh + dd * 512;
        float4 ka  = FI4(&ktr[l * 4]);
        float4 kb2 = FI4(&ktr[256 + l * 4]);
        float qv[4] = {q.x, q.y, q.z, q.w};
        float kv[8] = {ka.x, ka.y, ka.z, ka.w, kb2.x, kb2.y, kb2.z, kb2.w};
        #pragma unroll
        for (int r = 0; r < 4; ++r)
            #pragma unroll
            for (int j = 0; j < 8; ++j)
                acc[r][j] = fmaf(qv[r], kv[j], acc[r][j]);
    }

    #pragma unroll
    for (int pr = 0; pr < 2; ++pr) {
        const int ta = t0p + w4 + pr * 2;

        float sa[8], sb[8];
        {
            const float* ua = un + ((size_t)bh * 1536 + ta) * 512;
            float4 u0 = FI4(&ua[l * 4]);
            float4 u1 = FI4(&ua[256 + l * 4]);
            sa[0] = fmaf(acc[pr*2][0], S6, gumbelf(u0.x));
            sa[1] = fmaf(acc[pr*2][1], S6, gumbelf(u0.y));
            sa[2] = fmaf(acc[pr*2][2], S6, gumbelf(u0.z));
            sa[3] = fmaf(acc[pr*2][3], S6, gumbelf(u0.w));
            sa[4] = fmaf(acc[pr*2][4], S6, gumbelf(u1.x));
            sa[5] = fmaf(acc[pr*2][5], S6, gumbelf(u1.y));
            sa[6] = fmaf(acc[pr*2][6], S6, gumbelf(u1.z));
            sa[7] = fmaf(acc[pr*2][7], S6, gumbelf(u1.w));
        }
        {
            const float* ub = un + ((size_t)bh * 1536 + ta + 1) * 512;
            float4 u0 = FI4(&ub[l * 4]);
            float4 u1 = FI4(&ub[256 + l * 4]);
            sb[0] = fmaf(acc[pr*2+1][0], S6, gumbelf(u0.x));
            sb[1] = fmaf(acc[pr*2+1][1], S6, gumbelf(u0.y));
            sb[2] = fmaf(acc[pr*2+1][2], S6, gumbelf(u0.z));
            sb[3] = fmaf(acc[pr*2+1][3], S6, gumbelf(u0.w));
            sb[4] = fmaf(acc[pr*2+1][4], S6, gumbelf(u1.x));
            sb[5] = fmaf(acc[pr*2+1][5], S6, gumbelf(u1.y));
            sb[6] = fmaf(acc[pr*2+1][6], S6, gumbelf(u1.z));
            sb[7] = fmaf(acc[pr*2+1][7], S6, gumbelf(u1.w));
        }

        unsigned ua32[8], ub32[8];
        float mA = sa[0], mB = sb[0];
        #pragma unroll
        for (int j = 0; j < 8; ++j) {
            ua32[j] = ordkey(sa[j]); ub32[j] = ordkey(sb[j]);
            mA = fmaxf(mA, sa[j]); mB = fmaxf(mB, sb[j]);
        }
        mA = wave_max_bcast(mA);
        mB = wave_max_bcast(mB);

        unsigned long long selA[8], selB[8];
        select16(ua32, selA, ordkey(mA - 28.0f), ordkey(mA));
        select16(ub32, selB, ordkey(mB - 28.0f), ordkey(mB));

        // weights = exp(s - m); ratio identical to softmax
        float eAr[8], eBr[8], psA = 0.f, psB = 0.f;
        #pragma unroll
        for (int j = 0; j < 8; ++j) {
            float exa = __expf(sa[j] - mA);
            float exb = __expf(sb[j] - mB);
            eAr[j] = ((selA[j] >> l) & 1ull) ? exa : 0.f;
            eBr[j] = ((selB[j] >> l) & 1ull) ? exb : 0.f;
            psA += eAr[j]; psB += eBr[j];
        }
        float sumA = wave_sum_bcast(psA);
        float sumB = wave_sum_bcast(psB);

        // compact 16 (n, w) winners per row into LDS (ballot-rank)
        {
            int baseA = 0, baseB = 0;
            #pragma unroll
            for (int j = 0; j < 8; ++j) {
                unsigned long long ma = selA[j], mb = selB[j];
                int nj = ((j >> 2) << 8) + l * 4 + (j & 3);
                if ((ma >> l) & 1ull) {
                    int rank = baseA + mbcnt64(ma);
                    CmpN[wv][pr][0][rank] = nj;
                    CmpW[wv][pr][0][rank] = eAr[j];
                }
                if ((mb >> l) & 1ull) {
                    int rank = baseB + mbcnt64(mb);
                    CmpN[wv][pr][1][rank] = nj;
                    CmpW[wv][pr][1][rank] = eBr[j];
                }
                baseA += __popcll(ma); baseB += __popcll(mb);
            }
        }
        asm volatile("s_waitcnt lgkmcnt(0)" ::: "memory");

        // fixed 16-iter gather: independent V-row loads, full ILP
        float od = 0.f, od2 = 0.f;
        #pragma unroll
        for (int k = 0; k < 16; ++k) {
            int nn  = CmpN[wv][pr][halfw][k];
            float w = CmpW[wv][pr][halfw][k];
            const float* vr = Vbh + (size_t)nn * 36;
            od = fmaf(w, vr[dpv], od);
            if (dpv < 4) od2 = fmaf(w, vr[32 + dpv], od2);
        }

        float invs = 1.0f / (halfw ? sumB : sumA);
        int t = ta + halfw;
        _Float16* orow = att16 + ((size_t)b * 1536 + t) * 288 + h * 36;
        orow[dpv] = (_Float16)(od * invs);
        if (dpv < 4) orow[32 + dpv] = (_Float16)(od2 * invs);
    }
}

// ---------------------------------------------------------------------------
extern "C" void kernel_launch(void* const* d_in, const int* in_sizes, int n_in,
                              void* d_out, int out_size, void* d_ws, size_t ws_size,
                              hipStream_t stream)
{
    (void)in_sizes; (void)n_in; (void)out_size; (void)ws_size;
    const float* x1      = (const float*)d_in[0];
    const float* x2      = (const float*)d_in[1];
    const float* x3      = (const float*)d_in[2];
    const float* xf      = (const float*)d_in[3];
    const float* emb     = (const float*)d_in[4];
    const float* un      = (const float*)d_in[5];
    const float* adaln_w = (const float*)d_in[6];
    const float* adaln_b = (const float*)d_in[7];
    const float* xfn_w   = (const float*)d_in[8];
    const float* xfn_b   = (const float*)d_in[9];
    const float* q_w     = (const float*)d_in[10];
    const float* q_b     = (const float*)d_in[11];
    const float* k_w     = (const float*)d_in[12];
    const float* k_b     = (const float*)d_in[13];
    const float* v_w     = (const float*)d_in[14];
    const float* v_b     = (const float*)d_in[15];
    const float* out_w   = (const float*)d_in[16];
    const float* out_b   = (const float*)d_in[17];
    float* out = (float*)d_out;

    float* ws = (float*)d_ws;
    float* eo = ws;                          // 16,384 f32
    float* Qb = eo + 16384;                  // 1,769,472 f32
    float* Kt = Qb + 1769472;                // 589,824 f32  [bh][36][512]
    float* Vb = Kt + 589824;                 // 589,824 f32  [bh][512][36]
    _Float16* xnqh = (_Float16*)(Vb + 589824);   // 3,145,728 h
    _Float16* xnql = xnqh + 3145728;
    _Float16* xfnh = xnql + 3145728;         // 8,388,608 h
    _Float16* xfnl = xfnh + 8388608;
    _Float16* att16 = xfnl + 8388608;        // 1,769,472 h
    _Float16* qwh  = att16 + 1769472;        // 442,368 h
    _Float16* qwl  = qwh + 442368;
    _Float16* kwh  = qwl + 442368;           // 147,456 h
    _Float16* kwl  = kwh + 147456;
    _Float16* vw16 = kwl + 147456;           // 147,456 h
    _Float16* ow16 = vw16 + 147456;          // 442,368 h

    convw_kernel<<<4608, 256, 0, stream>>>(q_w, k_w, v_w, out_w,
                                           qwh, qwl, kwh, kwl, vw16, ow16);
    eo_kernel<<<4096, 256, 0, stream>>>(emb, adaln_w, adaln_b, xfn_w, xfn_b, eo);
    ln_kernel<<<22528, 256, 0, stream>>>(x1, x2, x3, xf, eo, xnqh, xnql, xfnh, xfnl);
    gemm16_kernel<3, 0><<<288, 256, 0, stream>>>(xnqh, xnql, qwh, qwl, q_b, Qb);
    gemm16_kernel<3, 1><<<128, 256, 0, stream>>>(xfnh, xfnl, kwh, kwl, k_b, Kt);
    gemm16_kernel<3, 2><<<128, 256, 0, stream>>>(xfnh, nullptr, vw16, nullptr, v_b, Vb);
    attn_kernel<<<1536, 512, 0, stream>>>(Qb, Kt, Vb, un, att16);
    gemm16_kernel<4, 3><<<384, 256, 0, stream>>>(att16, nullptr, ow16, nullptr, out_b, out);
}